// Round 17
// baseline (147.766 us; speedup 1.0000x reference)
//
#include <hip/hip_runtime.h>

typedef unsigned short ushort_t;
typedef unsigned int uint_t;
typedef __attribute__((ext_vector_type(8))) short s16x8;
typedef __attribute__((ext_vector_type(4))) short s16x4;
typedef __attribute__((ext_vector_type(4))) float f32x4;
typedef __attribute__((ext_vector_type(16))) float f32x16;

#define S_TOT 4096
#define QSCALE 0.08838834764831845f       // 1/sqrt(128)
#define LOG2E 1.4426950408889634f
#define QSL (QSCALE * LOG2E)              // baked into Q -> attn uses exp2
#define L2_10000_D16 0.8304820237218406f  // log2(10000)/16

__device__ __forceinline__ ushort_t f2b(float f) {
  uint_t u = __float_as_uint(f);
  uint_t r = (u + 0x7FFFu + ((u >> 16) & 1u)) >> 16;
  return (ushort_t)r;
}

__device__ __forceinline__ float b2f(ushort_t u) {
  return __uint_as_float((uint_t)u << 16);
}

__device__ __forceinline__ uint_t cvt_pk_bf16(float lo, float hi) {
  uint_t r;
  asm("v_cvt_pk_bf16_f32 %0, %1, %2" : "=v"(r) : "v"(lo), "v"(hi));
  return r;
}

__device__ __forceinline__ void gload16(const void* g, void* l) {
  __builtin_amdgcn_global_load_lds(
      (const __attribute__((address_space(1))) unsigned int*)g,
      (__attribute__((address_space(3))) unsigned int*)l, 16, 0, 0);
}

// table-driven rope pair: tab[src*16+j] = {sin(src*inv_j), cos(src*inv_j)}
__device__ __forceinline__ void rope_pair_t(float& x0, float& x1, int p, int hi, int wi,
                                            float scale, const float2* __restrict__ tab) {
  int j = p >> 1;
  int src = (p & 1) ? wi : hi;
  float2 sc = tab[src * 16 + j];
  float r0 = (x0 * sc.x - x1 * sc.y) * scale;
  float r1 = (x0 * sc.y + x1 * sc.x) * scale;
  x0 = r0; x1 = r1;
}

// ---------------------------------------------------------------------------
// K1: blocks 0..511: y_q / y_kv convs + per-channel partials (transposed pch).
// blocks 512..710: MLA weight ABSORPTION (bf16) + rope trig table + counter reset.
__global__ __launch_bounds__(256) void k_conv1(
    const float* __restrict__ x, const float* __restrict__ q1_w, const float* __restrict__ q1_b,
    const float* __restrict__ kv1_w, const float* __restrict__ kv1_b,
    float* __restrict__ y_q, float* __restrict__ y_kv, double* __restrict__ pch,
    const float* __restrict__ q2_w, const float* __restrict__ q2_b,
    const float* __restrict__ kvup_w, const float* __restrict__ kvup_b,
    const float* __restrict__ out_w, const float* __restrict__ out_b,
    ushort_t* __restrict__ wq2, ushort_t* __restrict__ wout,
    float* __restrict__ q2b2, float* __restrict__ outb2,
    float2* __restrict__ tab, uint_t* __restrict__ counter) {
  if (blockIdx.x >= 512) {
    int E = (blockIdx.x - 512) * 256 + threadIdx.x;
    if (E == 0) *counter = 0;            // reset last-block counter for k_redstats
    if (E < 16384) {            // wq2' (absorbed q2 weights), 512x32
      int oc = E >> 5, r = E & 31;
      int h = oc >> 7, d = oc & 127;
      float val;
      if (d < 64) {
        val = 0.f;
        for (int dd = 0; dd < 64; dd++)
          val += kvup_w[(h * 128 + dd) * 64 + d] * q2_w[(size_t)(h * 128 + dd) * 32 + r];
      } else {
        val = q2_w[(size_t)oc * 32 + r];
      }
      wq2[(size_t)oc * 32 + r] = f2b(val);
    } else if (E < 49152) {     // wout' (absorbed out conv), 128x256
      int e = E - 16384;
      int c = e >> 8, col = e & 255;
      int h = col >> 6, l = col & 63;
      float val = 0.f;
      for (int vd = 0; vd < 64; vd++)
        val += out_w[(size_t)c * 256 + h * 64 + vd] * kvup_w[(h * 128 + 64 + vd) * 64 + l];
      wout[(size_t)c * 256 + col] = f2b(val);
    } else if (E < 49664) {     // q2b'
      int oc = E - 49152;
      int h = oc >> 7, d = oc & 127;
      float val;
      if (d < 64) {
        val = 0.f;
        for (int dd = 0; dd < 64; dd++)
          val += kvup_w[(h * 128 + dd) * 64 + d] * q2_b[h * 128 + dd];
      } else val = q2_b[oc];
      q2b2[oc] = val;
    } else if (E < 49792) {     // outb'
      int c = E - 49664;
      float val = out_b[c];
      for (int j = 0; j < 256; j++) {
        int h = j >> 6, vd = j & 63;
        val += out_w[(size_t)c * 256 + j] * kvup_b[h * 128 + 64 + vd];
      }
      outb2[c] = val;
    } else if (E < 50816) {     // rope trig table (1024 entries)
      int i = E - 49792;
      int src = i >> 4, j = i & 15;
      float inv = exp2f(-(float)j * L2_10000_D16);
      float ang = (float)src * inv;
      tab[i] = make_float2(sinf(ang), cosf(ang));
    }
    return;
  }
  const int b = blockIdx.x >> 8, blk = blockIdx.x & 255, st = blk * 16;
  const int t = threadIdx.x, si = t & 15, g = t >> 4;
  __shared__ float xs[128][16];
#pragma unroll
  for (int i = 0; i < 8; i++) {
    int c = g + 16 * i;
    xs[c][si] = x[(size_t)(b * 128 + c) * S_TOT + st + si];
  }
  __syncthreads();
  float acc[10];
#pragma unroll
  for (int i = 0; i < 10; i++) {
    int oc = g * 10 + i;
    acc[i] = (oc < 32) ? q1_b[oc] : kv1_b[oc - 32];
  }
  const float4* q1w4 = (const float4*)q1_w;
  const float4* kv1w4 = (const float4*)kv1_w;
  for (int c4 = 0; c4 < 32; c4++) {
    float x0 = xs[c4 * 4 + 0][si], x1 = xs[c4 * 4 + 1][si];
    float x2 = xs[c4 * 4 + 2][si], x3 = xs[c4 * 4 + 3][si];
#pragma unroll
    for (int i = 0; i < 10; i++) {
      int oc = g * 10 + i;
      float4 wv = (oc < 32) ? q1w4[oc * 32 + c4] : kv1w4[(oc - 32) * 32 + c4];
      acc[i] += wv.x * x0 + wv.y * x1 + wv.z * x2 + wv.w * x3;
    }
  }
#pragma unroll
  for (int i = 0; i < 10; i++) {
    int oc = g * 10 + i;
    float a = acc[i];
    if (oc < 32) y_q[(size_t)(b * 32 + oc) * S_TOT + st + si] = a;
    else         y_kv[(size_t)(b * 128 + oc - 32) * S_TOT + st + si] = a;
    double s = a, q = (double)a * a;
#pragma unroll
    for (int o = 1; o < 16; o <<= 1) { s += __shfl_xor(s, o, 16); q += __shfl_xor(q, o, 16); }
    if (si == 0) {
      double* pt = pch + (size_t)(b * 160 + oc) * 512 + blk * 2;
      pt[0] = s; pt[1] = q;
    }
  }
}

// ---------------------------------------------------------------------------
// K2 fused: per-pair reduction (grid 320, coalesced over transposed pch);
// the LAST block to finish (device atomic) composes the group-norm affine
// coefficients. Deterministic: composition depends only on the complete SQ.
__global__ __launch_bounds__(256) void k_redstats(
    const double* __restrict__ pch, double* __restrict__ SQ,
    const float* __restrict__ qg, const float* __restrict__ qb,
    const float* __restrict__ kvg, const float* __restrict__ kvb,
    const float* __restrict__ kng, const float* __restrict__ knb,
    float* __restrict__ coef, uint_t* __restrict__ counter) {
  const int pair = blockIdx.x, tid = threadIdx.x;
  const int lane = tid & 63, wid = tid >> 6;
  {
    const double* p = pch + (size_t)pair * 512;
    double s = p[tid * 2], q = p[tid * 2 + 1];
#pragma unroll
    for (int o = 1; o < 64; o <<= 1) { s += __shfl_xor(s, o, 64); q += __shfl_xor(q, o, 64); }
    __shared__ double red[4][2];
    if (lane == 0) { red[wid][0] = s; red[wid][1] = q; }
    __syncthreads();
    if (tid == 0) {
      SQ[pair * 2]     = red[0][0] + red[1][0] + red[2][0] + red[3][0];
      SQ[pair * 2 + 1] = red[0][1] + red[1][1] + red[2][1] + red[3][1];
    }
  }
  __shared__ int isLast;
  if (tid == 0) {
    __threadfence();                       // publish SQ before signaling
    uint_t prev = atomicAdd(counter, 1u);  // device-scope
    isLast = (prev == 319u);
  }
  __syncthreads();
  if (!isLast) return;
  __threadfence();                         // acquire: all SQ writes visible
  __shared__ double Sh[2][160], Qh[2][160];
  for (int i = tid; i < 320; i += 256) {
    int b = i / 160, c = i % 160;
    Sh[b][c] = SQ[i * 2]; Qh[b][c] = SQ[i * 2 + 1];
  }
  __syncthreads();
  if (tid < 2) {
    int b = tid;
    float* cf = coef + b * 320;
    const double NS = 4096.0;
    double muq = 0, m2q = 0;
    for (int c = 0; c < 32; c++) { muq += Sh[b][c]; m2q += Qh[b][c]; }
    muq /= (32.0 * NS); m2q /= (32.0 * NS);
    double rstdq = 1.0 / sqrt(m2q - muq * muq + 1e-5);
    for (int c = 0; c < 32; c++) {
      double A = rstdq * (double)qg[c];
      cf[c] = (float)A; cf[32 + c] = (float)((double)qb[c] - muq * A);
    }
    double mukv = 0, m2kv = 0;
    for (int c = 0; c < 128; c++) { mukv += Sh[b][32 + c]; m2kv += Qh[b][32 + c]; }
    mukv /= (128.0 * NS); m2kv /= (128.0 * NS);
    double rstdkv = 1.0 / sqrt(m2kv - mukv * mukv + 1e-5);
    for (int c = 0; c < 64; c++) {
      double A = rstdkv * (double)kvg[c];
      cf[64 + c] = (float)A; cf[128 + c] = (float)((double)kvb[c] - mukv * A);
    }
    double mu2 = 0, m22 = 0;
    for (int c2 = 0; c2 < 64; c2++) {
      int c = 64 + c2;
      double a = rstdkv * (double)kvg[c], bb = (double)kvb[c] - mukv * a;
      double Ec = Sh[b][32 + c] / NS, M2c = Qh[b][32 + c] / NS;
      mu2 += a * Ec + bb;
      m22 += a * a * M2c + 2.0 * a * bb * Ec + bb * bb;
    }
    mu2 /= 64.0; m22 /= 64.0;
    double rstd2 = 1.0 / sqrt(m22 - mu2 * mu2 + 1e-5);
    for (int c2 = 0; c2 < 64; c2++) {
      int c = 64 + c2;
      double a = rstdkv * (double)kvg[c], bb = (double)kvb[c] - mukv * a;
      cf[192 + c2] = (float)(a * rstd2 * (double)kng[c2]);
      cf[256 + c2] = (float)((bb - mu2) * rstd2 * (double)kng[c2] + (double)knb[c2]);
    }
  }
}

// ---------------------------------------------------------------------------
// K3 merged: blocks 0..511 = Q build (MFMA GEMM, absorbed weights);
// blocks 512..639 = latent build. Shared static LDS 24 KB. Table-driven rope.
__device__ __forceinline__ void gq_body(
    int id, ushort_t* smem,
    const float* __restrict__ y_q, const float* __restrict__ coef,
    const ushort_t* __restrict__ wq2, const float* __restrict__ q2b2,
    const float2* __restrict__ tab, ushort_t* __restrict__ Q) {
  const int h = id & 3, st = (id >> 2) & 63, b = id >> 8;
  const int t = threadIdx.x, si = t & 63, wid = t >> 6;
  const int l15 = t & 15, lg = (t >> 4) & 3;
  const float* cf = coef + b * 320;
  ushort_t* Xt = smem;           // [64][64]
  ushort_t* sQ = smem + 4096;    // [64][128]
  {
    ushort_t pk[8];
#pragma unroll
    for (int j = 0; j < 8; j++) {
      int c = wid * 8 + j;
      float v = y_q[(size_t)(b * 32 + c) * S_TOT + st * 64 + si];
      pk[j] = f2b(v * cf[c] + cf[32 + c]);
    }
    *(s16x8*)((char*)(Xt + si * 64) + ((wid * 16) ^ ((si & 7) << 4))) = *(s16x8*)pk;
  }
  __syncthreads();
  const int d0w = wid * 32;
  f32x4 acc[2][4];
#pragma unroll
  for (int db = 0; db < 2; db++) {
    f32x4 bv;
#pragma unroll
    for (int r = 0; r < 4; r++) bv[r] = q2b2[h * 128 + d0w + db * 16 + lg * 4 + r];
#pragma unroll
    for (int sb = 0; sb < 4; sb++) acc[db][sb] = bv;
  }
  s16x8 wf[2];
#pragma unroll
  for (int db = 0; db < 2; db++)
    wf[db] = *(const s16x8*)(wq2 + (size_t)(h * 128 + d0w + db * 16 + l15) * 32 + lg * 8);
  const int xsw = (lg * 16) ^ ((l15 & 7) << 4);
#pragma unroll
  for (int sb = 0; sb < 4; sb++) {
    s16x8 xf = *(const s16x8*)((const char*)(Xt + (sb * 16 + l15) * 64) + xsw);
#pragma unroll
    for (int db = 0; db < 2; db++)
      acc[db][sb] = __builtin_amdgcn_mfma_f32_16x16x32_bf16(wf[db], xf, acc[db][sb], 0, 0, 0);
  }
  if (wid >= 2) {
#pragma unroll
    for (int db = 0; db < 2; db++)
#pragma unroll
      for (int sb = 0; sb < 4; sb++) {
        int sp = st * 64 + sb * 16 + l15, hi = sp >> 6, wi = sp & 63;
        int dg = d0w + db * 16 + lg * 4;
#pragma unroll
        for (int pr = 0; pr < 2; pr++) {
          float v0 = acc[db][sb][pr * 2], v1 = acc[db][sb][pr * 2 + 1];
          int p = (dg + pr * 2 - 64) >> 1;
          rope_pair_t(v0, v1, p, hi, wi, QSL, tab);
          acc[db][sb][pr * 2] = v0; acc[db][sb][pr * 2 + 1] = v1;
        }
      }
  } else {
#pragma unroll
    for (int db = 0; db < 2; db++)
#pragma unroll
      for (int sb = 0; sb < 4; sb++)
#pragma unroll
        for (int r = 0; r < 4; r++) acc[db][sb][r] *= QSL;
  }
#pragma unroll
  for (int db = 0; db < 2; db++)
#pragma unroll
    for (int sb = 0; sb < 4; sb++) {
      ushort_t pk[4];
#pragma unroll
      for (int r = 0; r < 4; r++) pk[r] = f2b(acc[db][sb][r]);
      int srow = sb * 16 + l15;
      *(s16x4*)((char*)(sQ + srow * 128) + (((d0w + db * 16 + lg * 4) * 2) ^ ((srow & 7) << 4))) =
          *(s16x4*)pk;
    }
  __syncthreads();
  ushort_t* qrow = Q + ((size_t)(b * 4 + h) * S_TOT + st * 64 + si) * 128 + wid * 32;
#pragma unroll
  for (int j = 0; j < 4; j++) {
    s16x8 v = *(const s16x8*)((const char*)(sQ + si * 128) + ((wid * 64 + j * 16) ^ ((si & 7) << 4)));
    *(s16x8*)(qrow + j * 8) = v;
  }
}

__device__ __forceinline__ void lat_body(
    int blk, const float* __restrict__ y_kv, const float* __restrict__ coef,
    const float2* __restrict__ tab, ushort_t* __restrict__ C, ushort_t* __restrict__ VT) {
  const int b = blk >> 6, st = (blk & 63) * 64;
  const int t = threadIdx.x, si = t & 63, g = t >> 6;
  const float* cf = coef + b * 320;
  const int sp = st + si;
  if (g < 2) {
    const int c0 = g * 32;
    float v[32];
#pragma unroll
    for (int j = 0; j < 32; j++) {
      int c = c0 + j;
      v[j] = y_kv[(size_t)(b * 128 + c) * S_TOT + sp] * cf[64 + c] + cf[128 + c];
    }
    const int hi = sp >> 6, wi = sp & 63;
#pragma unroll
    for (int k = 0; k < 16; k++)
      rope_pair_t(v[2 * k], v[2 * k + 1], (c0 >> 1) + k, hi, wi, 1.0f, tab);
    ushort_t pk[32];
#pragma unroll
    for (int j = 0; j < 32; j++) pk[j] = f2b(v[j]);
    ushort_t* crow = C + (size_t)(b * S_TOT + sp) * 128 + 64 + c0;
#pragma unroll
    for (int j4 = 0; j4 < 4; j4++) *(s16x8*)(crow + j4 * 8) = *(s16x8*)(pk + j4 * 8);
  } else {
    const int c0 = (g - 2) * 32;
    ushort_t pk[32];
#pragma unroll
    for (int j = 0; j < 32; j++) {
      int c2 = c0 + j;
      float v = y_kv[(size_t)(b * 128 + 64 + c2) * S_TOT + sp] * cf[192 + c2] + cf[256 + c2];
      ushort_t u = f2b(v);
      pk[j] = u;
      VT[(size_t)(b * 64 + c2) * S_TOT + sp] = u;
    }
    ushort_t* crow = C + (size_t)(b * S_TOT + sp) * 128 + c0;
#pragma unroll
    for (int j4 = 0; j4 < 4; j4++) *(s16x8*)(crow + j4 * 8) = *(s16x8*)(pk + j4 * 8);
  }
}

__global__ __launch_bounds__(256) void k_build(
    const float* __restrict__ y_q, const float* __restrict__ y_kv,
    const float* __restrict__ coef,
    const ushort_t* __restrict__ wq2, const float* __restrict__ q2b2,
    const float2* __restrict__ tab,
    ushort_t* __restrict__ Q, ushort_t* __restrict__ C, ushort_t* __restrict__ VT) {
  __shared__ __align__(16) ushort_t smem[12288];  // 24 KB
  if (blockIdx.x < 512) gq_body(blockIdx.x, smem, y_q, coef, wq2, q2b2, tab, Q);
  else                  lat_body(blockIdx.x - 512, y_kv, coef, tab, C, VT);
}

// ---------------------------------------------------------------------------
// K5: flash attention over shared latent (round-13 structure).
// 32x32 MFMA, QBLK=32/wave, 4 waves; triple-buffered counted-vmcnt pipeline;
// fixed-reference softmax (exp2 direct); P via cvt_pk + permlane32_swap.
// Output UNNORMALIZED (bf16) + per-row l; k_oc divides by (l0+l1).
// grid 512 = 2 half x 8 bh x 32 qblk. LDS 72 KB.
__global__ __launch_bounds__(256, 2) void k_attn(
    const ushort_t* __restrict__ Q, const ushort_t* __restrict__ C,
    const ushort_t* __restrict__ VT, ushort_t* __restrict__ Opart,
    float* __restrict__ lvec) {
  const int bid = blockIdx.x;
  const int bh = bid & 7;                  // XCD swizzle: one bh per XCD
  const int rest = bid >> 3;               // [0,64)
  const int half = rest >> 5, qblk = rest & 31;
  const int kv0 = half * 2048;
  const int tid = threadIdx.x;
  const int wid = tid >> 6, lane = tid & 63;
  const int l31 = lane & 31, hi = lane >> 5;
  const int qbase = qblk * 128 + wid * 32;
  const int b4 = bh >> 2;                  // batch index
  const ushort_t* Qp = Q + (size_t)bh * S_TOT * 128;
  const ushort_t* Kp = C + (size_t)b4 * S_TOT * 128;
  const ushort_t* Vp = VT + (size_t)b4 * 64 * S_TOT;

  __shared__ __align__(16) ushort_t K_lds[3][64][128];  // 48 KB
  __shared__ __align__(16) ushort_t V_lds[3][64][64];   // 24 KB

  s16x8 qf[8];
#pragma unroll
  for (int c = 0; c < 8; c++)
    qf[c] = *(const s16x8*)(Qp + (size_t)(qbase + l31) * 128 + c * 16 + hi * 8);

  f32x16 o0, o1;
#pragma unroll
  for (int r = 0; r < 16; r++) { o0[r] = 0.f; o1[r] = 0.f; }
  float l_s = 0.f;

  const int krow_l = tid >> 4;   // +i*16
  const int kcolb = (tid & 15) * 16;
  const int vrow_l = tid >> 3;   // +i*32
  const int vcolb = (tid & 7) * 16;

#define STAGE(kvb, bufi)                                                          \
  {                                                                               \
    _Pragma("unroll")                                                             \
    for (int i = 0; i < 4; i++) {                                                 \
      int row = i * 16 + krow_l;                                                  \
      int colb = kcolb ^ ((row & 15) << 4);                                       \
      gload16((const char*)(Kp + (size_t)((kvb) + row) * 128) + colb,             \
              (void*)&K_lds[bufi][i * 16 + wid * 4][0]);                          \
    }                                                                             \
    _Pragma("unroll")                                                             \
    for (int i = 0; i < 2; i++) {                                                 \
      int vd = i * 32 + vrow_l;                                                   \
      int colb = vcolb ^ ((vd & 7) << 4);                                         \
      gload16((const char*)(Vp + (size_t)vd * S_TOT + (kvb)) + colb,              \
              (void*)&V_lds[bufi][i * 32 + wid * 8][0]);                          \
    }                                                                             \
  }

  STAGE(kv0, 0);            // 6 loads
  STAGE(kv0 + 64, 1);       // 12 outstanding

  const int kswz = (l31 & 15) << 4;
  const int vswz = (l31 & 7) << 4;
#pragma unroll 1
  for (int t = 0; t < 32; t++) {
    const int buf = t % 3;
    if (t < 31) {
      asm volatile("s_waitcnt vmcnt(6)" ::: "memory");   // own buf-t loads done
    } else {
      asm volatile("s_waitcnt vmcnt(0)" ::: "memory");
    }
    __builtin_amdgcn_sched_barrier(0);
    __builtin_amdgcn_s_barrier();          // publishes everyone's buf-t loads
    __builtin_amdgcn_sched_barrier(0);
    if (t < 30) STAGE(kv0 + (t + 2) * 64, (t + 2) % 3);  // flies for ~2 iters
    f32x16 sc0, sc1;
#pragma unroll
    for (int r = 0; r < 16; r++) { sc0[r] = 0.f; sc1[r] = 0.f; }
    __builtin_amdgcn_s_setprio(1);
#pragma unroll
    for (int c = 0; c < 8; c++) {
      const int off = (c * 32 + hi * 16) ^ kswz;
      s16x8 k0 = *(const s16x8*)((const char*)&K_lds[buf][l31][0] + off);
      s16x8 k1 = *(const s16x8*)((const char*)&K_lds[buf][32 + l31][0] + off);
      sc0 = __builtin_amdgcn_mfma_f32_32x32x16_bf16(k0, qf[c], sc0, 0, 0, 0);
      sc1 = __builtin_amdgcn_mfma_f32_32x32x16_bf16(k1, qf[c], sc1, 0, 0, 0);
    }
    __builtin_amdgcn_s_setprio(0);
    // fixed-reference softmax numerator: P = exp2(s) directly
    float rs = 0.f;
#pragma unroll
    for (int r = 0; r < 16; r++) {
      float p0 = exp2f(sc0[r]);
      float p1 = exp2f(sc1[r]);
      sc0[r] = p0; sc1[r] = p1;
      rs += p0 + p1;
    }
    l_s += rs;
    __builtin_amdgcn_s_setprio(1);
#pragma unroll
    for (int c = 0; c < 4; c++) {
      const f32x16 P = (c < 2) ? sc0 : sc1;
      const int rA = 8 * (c & 1);
      uint_t a0 = cvt_pk_bf16(P[rA + 0], P[rA + 1]);
      uint_t a1 = cvt_pk_bf16(P[rA + 2], P[rA + 3]);
      uint_t b0 = cvt_pk_bf16(P[rA + 4], P[rA + 5]);
      uint_t b1 = cvt_pk_bf16(P[rA + 6], P[rA + 7]);
      asm volatile("v_permlane32_swap_b32 %0, %1" : "+v"(a0), "+v"(b0));
      asm volatile("v_permlane32_swap_b32 %0, %1" : "+v"(a1), "+v"(b1));
      union { uint_t u[4]; s16x8 v; } pf;
      pf.u[0] = a0; pf.u[1] = a1;
      pf.u[2] = b0; pf.u[3] = b1;
      const int voff = (c * 32 + hi * 16) ^ vswz;
      s16x8 v0 = *(const s16x8*)((const char*)&V_lds[buf][l31][0] + voff);
      s16x8 v1 = *(const s16x8*)((const char*)&V_lds[buf][32 + l31][0] + voff);
      o0 = __builtin_amdgcn_mfma_f32_32x32x16_bf16(v0, pf.v, o0, 0, 0, 0);
      o1 = __builtin_amdgcn_mfma_f32_32x32x16_bf16(v1, pf.v, o1, 0, 0, 0);
    }
    __builtin_amdgcn_s_setprio(0);
  }
#undef STAGE
  l_s += __shfl_xor(l_s, 32, 64);
  if (lane < 32)
    lvec[((size_t)(half * 8 + bh) << 12) + qbase + l31] = l_s;
  // O^T -> O epilogue via LDS bounce (reuse K_lds[0]); UNNORMALIZED output
  char* sO = (char*)&K_lds[0][0][0];
#pragma unroll
  for (int vt = 0; vt < 2; vt++) {
#pragma unroll
    for (int r = 0; r < 16; r += 2) {
      float v0 = (vt ? o1[r] : o0[r]);
      float v1 = (vt ? o1[r + 1] : o0[r + 1]);
      uint_t u = cvt_pk_bf16(v0, v1);
      int vd = vt * 32 + (r & 3) + 8 * (r >> 2) + 4 * hi;
      *(uint_t*)(sO + (wid * 32 + l31) * 128 + ((vd * 2) ^ ((l31 & 7) << 4))) = u;
    }
  }
  __syncthreads();
  {
    const int r = tid >> 1, hf = tid & 1;
    const int w = r >> 5, ql = r & 31;
    ushort_t* orow = Opart + ((size_t)(half * 8 + bh) * S_TOT + qblk * 128 + r) * 64 + hf * 32;
#pragma unroll
    for (int j = 0; j < 4; j++) {
      s16x8 v = *(const s16x8*)(sO + (w * 32 + ql) * 128 + ((hf * 64 + j * 16) ^ ((ql & 7) << 4)));
      *(s16x8*)(orow + j * 8) = v;
    }
  }
}

// ---------------------------------------------------------------------------
// K6: out conv (absorbed W_v) + fused combine: X = (O0_raw + O1_raw)/(l0+l1).
__global__ __launch_bounds__(256) void k_oc(
    const ushort_t* __restrict__ Opart, const float* __restrict__ lvec,
    const ushort_t* __restrict__ wout, const float* __restrict__ outb2,
    const float* __restrict__ x, float* __restrict__ out) {
  const int id = blockIdx.x;
  const int cch = id & 1, st32 = (id >> 1) & 127, b = id >> 8;
  const int t = threadIdx.x, wid = t >> 6;
  const int l15 = t & 15, lg = (t >> 4) & 3;
  __shared__ __align__(16) ushort_t Xt[32][256];
  {
    const int s = t & 31, grp = t >> 5;
    const int h = grp >> 1, vd0 = (grp & 1) * 32;
    const int sp = st32 * 32 + s;
    const float l0 = lvec[((size_t)(b * 4 + h) << 12) + sp];
    const float l1 = lvec[((size_t)(8 + b * 4 + h) << 12) + sp];
    const float w = 1.f / (l0 + l1);
    const ushort_t* oa = Opart + ((size_t)(b * 4 + h) * S_TOT + sp) * 64 + vd0;
    const ushort_t* obp = oa + (size_t)8 * S_TOT * 64;
#pragma unroll
    for (int j4 = 0; j4 < 4; j4++) {
      union { s16x8 v; ushort_t u[8]; } av, bv2;
      av.v = *(const s16x8*)(oa + j4 * 8);
      bv2.v = *(const s16x8*)(obp + j4 * 8);
      ushort_t pk[8];
#pragma unroll
      for (int j = 0; j < 8; j++) pk[j] = f2b(w * (b2f(av.u[j]) + b2f(bv2.u[j])));
      *(s16x8*)((char*)&Xt[s][0] + ((grp * 64 + j4 * 16) ^ ((s & 7) << 4))) = *(s16x8*)pk;
    }
  }
  __syncthreads();
  const int c0w = cch * 64 + wid * 16;
  f32x4 acc[2];
  {
    f32x4 bv;
#pragma unroll
    for (int r = 0; r < 4; r++) bv[r] = outb2[c0w + lg * 4 + r];
    acc[0] = bv; acc[1] = bv;
  }
#pragma unroll
  for (int kk = 0; kk < 8; kk++) {
    s16x8 wf = *(const s16x8*)(wout + (size_t)(c0w + l15) * 256 + kk * 32 + lg * 8);
#pragma unroll
    for (int sb = 0; sb < 2; sb++) {
      s16x8 xf = *(const s16x8*)((const char*)&Xt[sb * 16 + l15][0] +
                                 ((kk * 64 + lg * 16) ^ ((l15 & 7) << 4)));
      acc[sb] = __builtin_amdgcn_mfma_f32_16x16x32_bf16(wf, xf, acc[sb], 0, 0, 0);
    }
  }
#pragma unroll
  for (int sb = 0; sb < 2; sb++) {
#pragma unroll
    for (int r = 0; r < 4; r++) {
      int c = c0w + lg * 4 + r;
      int sp = st32 * 32 + sb * 16 + l15;
      size_t idx = (size_t)(b * 128 + c) * S_TOT + sp;
      out[idx] = acc[sb][r] + x[idx];
    }
  }
}

// ---------------------------------------------------------------------------
extern "C" void kernel_launch(void* const* d_in, const int* in_sizes, int n_in,
                              void* d_out, int out_size, void* d_ws, size_t ws_size,
                              hipStream_t stream) {
  const float* x      = (const float*)d_in[0];
  const float* q1_w   = (const float*)d_in[1];
  const float* q1_b   = (const float*)d_in[2];
  const float* q_gn_g = (const float*)d_in[3];
  const float* q_gn_b = (const float*)d_in[4];
  const float* q2_w   = (const float*)d_in[5];
  const float* q2_b   = (const float*)d_in[6];
  const float* kv1_w  = (const float*)d_in[7];
  const float* kv1_b  = (const float*)d_in[8];
  const float* kv_gn_g= (const float*)d_in[9];
  const float* kv_gn_b= (const float*)d_in[10];
  const float* kvn_g  = (const float*)d_in[11];
  const float* kvn_b  = (const float*)d_in[12];
  const float* kvup_w = (const float*)d_in[13];
  const float* kvup_b = (const float*)d_in[14];
  const float* out_w  = (const float*)d_in[15];
  const float* out_b  = (const float*)d_in[16];

  const size_t MB = 1u << 20;
  char* ws = (char*)d_ws;
  float*    y_q   = (float*)(ws);                           // 0..1 MB
  float*    y_kv  = (float*)(ws + 1 * MB);                  // 1..5 MB
  ushort_t* Q     = (ushort_t*)(ws + 5 * MB);               // 5..13 MB
  ushort_t* C     = (ushort_t*)(ws + 13 * MB);              // 13..15 MB (latent+rope)
  ushort_t* VT    = (ushort_t*)(ws + 15 * MB);              // 15..16 MB (latent^T)
  double*   pch   = (double*)(ws + 17 * MB);                // 17..18.25 MB
  double*   SQ    = (double*)(ws + 19 * MB);                // 5 KB
  float*    coef  = (float*)(ws + 19 * MB + 8192);          // 2.5 KB
  ushort_t* wq2   = (ushort_t*)(ws + 19 * MB + 16384);      // 32 KB
  ushort_t* wout  = (ushort_t*)(ws + 19 * MB + 65536);      // 64 KB
  float*    q2b2  = (float*)(ws + 19 * MB + 131072);        // 2 KB
  float*    outb2 = (float*)(ws + 19 * MB + 139264);        // 512 B
  float2*   tab   = (float2*)(ws + 19 * MB + 143360);       // 8 KB rope trig table
  uint_t*   ctr   = (uint_t*)(ws + 19 * MB + 151552);       // 4 B last-block counter
  ushort_t* Opart = (ushort_t*)(ws + 20 * MB);              // 20..28 MB
  float*    lvec  = (float*)(ws + 28 * MB);                 // 256 KB
  float*    out   = (float*)d_out;

  k_conv1   <<<711, 256, 0, stream>>>(x, q1_w, q1_b, kv1_w, kv1_b, y_q, y_kv, pch,
                                      q2_w, q2_b, kvup_w, kvup_b, out_w, out_b,
                                      wq2, wout, q2b2, outb2, tab, ctr);
  k_redstats<<<320, 256, 0, stream>>>(pch, SQ, q_gn_g, q_gn_b, kv_gn_g, kv_gn_b,
                                      kvn_g, kvn_b, coef, ctr);
  k_build   <<<640, 256, 0, stream>>>(y_q, y_kv, coef, wq2, q2b2, tab, Q, C, VT);
  k_attn    <<<512, 256, 0, stream>>>(Q, C, VT, Opart, lvec);
  k_oc      <<<512, 256, 0, stream>>>(Opart, lvec, wout, outb2, x, out);
}

// Round 18
// 142.550 us; speedup vs baseline: 1.0366x; 1.0366x over previous
//
#include <hip/hip_runtime.h>

typedef unsigned short ushort_t;
typedef unsigned int uint_t;
typedef __attribute__((ext_vector_type(8))) short s16x8;
typedef __attribute__((ext_vector_type(4))) short s16x4;
typedef __attribute__((ext_vector_type(4))) float f32x4;
typedef __attribute__((ext_vector_type(16))) float f32x16;

#define S_TOT 4096
#define QSCALE 0.08838834764831845f       // 1/sqrt(128)
#define LOG2E 1.4426950408889634f
#define QSL (QSCALE * LOG2E)              // baked into Q -> attn uses exp2
#define L2_10000_D16 0.8304820237218406f  // log2(10000)/16

__device__ __forceinline__ ushort_t f2b(float f) {
  uint_t u = __float_as_uint(f);
  uint_t r = (u + 0x7FFFu + ((u >> 16) & 1u)) >> 16;
  return (ushort_t)r;
}

__device__ __forceinline__ float b2f(ushort_t u) {
  return __uint_as_float((uint_t)u << 16);
}

__device__ __forceinline__ uint_t cvt_pk_bf16(float lo, float hi) {
  uint_t r;
  asm("v_cvt_pk_bf16_f32 %0, %1, %2" : "=v"(r) : "v"(lo), "v"(hi));
  return r;
}

__device__ __forceinline__ void gload16(const void* g, void* l) {
  __builtin_amdgcn_global_load_lds(
      (const __attribute__((address_space(1))) unsigned int*)g,
      (__attribute__((address_space(3))) unsigned int*)l, 16, 0, 0);
}

// table-driven rope pair: tab[src*16+j] = {sin(src*inv_j), cos(src*inv_j)}
__device__ __forceinline__ void rope_pair_t(float& x0, float& x1, int p, int hi, int wi,
                                            float scale, const float2* __restrict__ tab) {
  int j = p >> 1;
  int src = (p & 1) ? wi : hi;
  float2 sc = tab[src * 16 + j];
  float r0 = (x0 * sc.x - x1 * sc.y) * scale;
  float r1 = (x0 * sc.y + x1 * sc.x) * scale;
  x0 = r0; x1 = r1;
}

// ---------------------------------------------------------------------------
// K1: blocks 0..511: y_q / y_kv convs + per-channel partials (transposed pch).
// blocks 512..706: MLA weight ABSORPTION (bf16).
__global__ __launch_bounds__(256) void k_conv1(
    const float* __restrict__ x, const float* __restrict__ q1_w, const float* __restrict__ q1_b,
    const float* __restrict__ kv1_w, const float* __restrict__ kv1_b,
    float* __restrict__ y_q, float* __restrict__ y_kv, double* __restrict__ pch,
    const float* __restrict__ q2_w, const float* __restrict__ q2_b,
    const float* __restrict__ kvup_w, const float* __restrict__ kvup_b,
    const float* __restrict__ out_w, const float* __restrict__ out_b,
    ushort_t* __restrict__ wq2, ushort_t* __restrict__ wout,
    float* __restrict__ q2b2, float* __restrict__ outb2) {
  if (blockIdx.x >= 512) {
    int E = (blockIdx.x - 512) * 256 + threadIdx.x;
    if (E < 16384) {            // wq2' (absorbed q2 weights), 512x32
      int oc = E >> 5, r = E & 31;
      int h = oc >> 7, d = oc & 127;
      float val;
      if (d < 64) {
        val = 0.f;
        for (int dd = 0; dd < 64; dd++)
          val += kvup_w[(h * 128 + dd) * 64 + d] * q2_w[(size_t)(h * 128 + dd) * 32 + r];
      } else {
        val = q2_w[(size_t)oc * 32 + r];
      }
      wq2[(size_t)oc * 32 + r] = f2b(val);
    } else if (E < 49152) {     // wout' (absorbed out conv), 128x256
      int e = E - 16384;
      int c = e >> 8, col = e & 255;
      int h = col >> 6, l = col & 63;
      float val = 0.f;
      for (int vd = 0; vd < 64; vd++)
        val += out_w[(size_t)c * 256 + h * 64 + vd] * kvup_w[(h * 128 + 64 + vd) * 64 + l];
      wout[(size_t)c * 256 + col] = f2b(val);
    } else if (E < 49664) {     // q2b'
      int oc = E - 49152;
      int h = oc >> 7, d = oc & 127;
      float val;
      if (d < 64) {
        val = 0.f;
        for (int dd = 0; dd < 64; dd++)
          val += kvup_w[(h * 128 + dd) * 64 + d] * q2_b[h * 128 + dd];
      } else val = q2_b[oc];
      q2b2[oc] = val;
    } else if (E < 49792) {     // outb'
      int c = E - 49664;
      float val = out_b[c];
      for (int j = 0; j < 256; j++) {
        int h = j >> 6, vd = j & 63;
        val += out_w[(size_t)c * 256 + j] * kvup_b[h * 128 + 64 + vd];
      }
      outb2[c] = val;
    }
    return;
  }
  const int b = blockIdx.x >> 8, blk = blockIdx.x & 255, st = blk * 16;
  const int t = threadIdx.x, si = t & 15, g = t >> 4;
  __shared__ float xs[128][16];
#pragma unroll
  for (int i = 0; i < 8; i++) {
    int c = g + 16 * i;
    xs[c][si] = x[(size_t)(b * 128 + c) * S_TOT + st + si];
  }
  __syncthreads();
  float acc[10];
#pragma unroll
  for (int i = 0; i < 10; i++) {
    int oc = g * 10 + i;
    acc[i] = (oc < 32) ? q1_b[oc] : kv1_b[oc - 32];
  }
  const float4* q1w4 = (const float4*)q1_w;
  const float4* kv1w4 = (const float4*)kv1_w;
  for (int c4 = 0; c4 < 32; c4++) {
    float x0 = xs[c4 * 4 + 0][si], x1 = xs[c4 * 4 + 1][si];
    float x2 = xs[c4 * 4 + 2][si], x3 = xs[c4 * 4 + 3][si];
#pragma unroll
    for (int i = 0; i < 10; i++) {
      int oc = g * 10 + i;
      float4 wv = (oc < 32) ? q1w4[oc * 32 + c4] : kv1w4[(oc - 32) * 32 + c4];
      acc[i] += wv.x * x0 + wv.y * x1 + wv.z * x2 + wv.w * x3;
    }
  }
#pragma unroll
  for (int i = 0; i < 10; i++) {
    int oc = g * 10 + i;
    float a = acc[i];
    if (oc < 32) y_q[(size_t)(b * 32 + oc) * S_TOT + st + si] = a;
    else         y_kv[(size_t)(b * 128 + oc - 32) * S_TOT + st + si] = a;
    double s = a, q = (double)a * a;
#pragma unroll
    for (int o = 1; o < 16; o <<= 1) { s += __shfl_xor(s, o, 16); q += __shfl_xor(q, o, 16); }
    if (si == 0) {
      double* pt = pch + (size_t)(b * 160 + oc) * 512 + blk * 2;
      pt[0] = s; pt[1] = q;
    }
  }
}

// ---------------------------------------------------------------------------
// K2a: parallel reduction over transposed pch. grid 320 (pair), coalesced.
__global__ __launch_bounds__(256) void k_red(
    const double* __restrict__ pch, double* __restrict__ SQ) {
  const int pair = blockIdx.x, tid = threadIdx.x;
  const int lane = tid & 63, wid = tid >> 6;
  const double* p = pch + (size_t)pair * 512;
  double s = p[tid * 2], q = p[tid * 2 + 1];
#pragma unroll
  for (int o = 1; o < 64; o <<= 1) { s += __shfl_xor(s, o, 64); q += __shfl_xor(q, o, 64); }
  __shared__ double red[4][2];
  if (lane == 0) { red[wid][0] = s; red[wid][1] = q; }
  __syncthreads();
  if (tid == 0) {
    SQ[pair * 2]     = red[0][0] + red[1][0] + red[2][0] + red[3][0];
    SQ[pair * 2 + 1] = red[0][1] + red[1][1] + red[2][1] + red[3][1];
  }
}

// K2b: compose group-norms into per-channel affine coefs + fill rope trig
// table: tab[src*16+j] = {sin(src*inv_j), cos(src*inv_j)}, src in 0..63.
__global__ __launch_bounds__(512) void k_stats(
    const double* __restrict__ SQ,
    const float* __restrict__ qg, const float* __restrict__ qb,
    const float* __restrict__ kvg, const float* __restrict__ kvb,
    const float* __restrict__ kng, const float* __restrict__ knb,
    float* __restrict__ coef, float2* __restrict__ tab) {
  __shared__ double Sh[2][160], Qh[2][160];
  const int tid = threadIdx.x;
  for (int i = tid; i < 1024; i += 512) {
    int src = i >> 4, j = i & 15;
    float inv = exp2f(-(float)j * L2_10000_D16);
    float ang = (float)src * inv;
    tab[i] = make_float2(sinf(ang), cosf(ang));
  }
  if (tid < 320) {
    int b = tid / 160, c = tid % 160;
    Sh[b][c] = SQ[tid * 2]; Qh[b][c] = SQ[tid * 2 + 1];
  }
  __syncthreads();
  if (tid < 2) {
    int b = tid;
    float* cf = coef + b * 320;
    const double NS = 4096.0;
    double muq = 0, m2q = 0;
    for (int c = 0; c < 32; c++) { muq += Sh[b][c]; m2q += Qh[b][c]; }
    muq /= (32.0 * NS); m2q /= (32.0 * NS);
    double rstdq = 1.0 / sqrt(m2q - muq * muq + 1e-5);
    for (int c = 0; c < 32; c++) {
      double A = rstdq * (double)qg[c];
      cf[c] = (float)A; cf[32 + c] = (float)((double)qb[c] - muq * A);
    }
    double mukv = 0, m2kv = 0;
    for (int c = 0; c < 128; c++) { mukv += Sh[b][32 + c]; m2kv += Qh[b][32 + c]; }
    mukv /= (128.0 * NS); m2kv /= (128.0 * NS);
    double rstdkv = 1.0 / sqrt(m2kv - mukv * mukv + 1e-5);
    for (int c = 0; c < 64; c++) {
      double A = rstdkv * (double)kvg[c];
      cf[64 + c] = (float)A; cf[128 + c] = (float)((double)kvb[c] - mukv * A);
    }
    double mu2 = 0, m22 = 0;
    for (int c2 = 0; c2 < 64; c2++) {
      int c = 64 + c2;
      double a = rstdkv * (double)kvg[c], bb = (double)kvb[c] - mukv * a;
      double Ec = Sh[b][32 + c] / NS, M2c = Qh[b][32 + c] / NS;
      mu2 += a * Ec + bb;
      m22 += a * a * M2c + 2.0 * a * bb * Ec + bb * bb;
    }
    mu2 /= 64.0; m22 /= 64.0;
    double rstd2 = 1.0 / sqrt(m22 - mu2 * mu2 + 1e-5);
    for (int c2 = 0; c2 < 64; c2++) {
      int c = 64 + c2;
      double a = rstdkv * (double)kvg[c], bb = (double)kvb[c] - mukv * a;
      cf[192 + c2] = (float)(a * rstd2 * (double)kng[c2]);
      cf[256 + c2] = (float)((bb - mu2) * rstd2 * (double)kng[c2] + (double)knb[c2]);
    }
  }
}

// ---------------------------------------------------------------------------
// K3 merged: blocks 0..511 = Q build (MFMA GEMM, absorbed weights);
// blocks 512..639 = latent build. Shared static LDS 24 KB. Table-driven rope.
__device__ __forceinline__ void gq_body(
    int id, ushort_t* smem,
    const float* __restrict__ y_q, const float* __restrict__ coef,
    const ushort_t* __restrict__ wq2, const float* __restrict__ q2b2,
    const float2* __restrict__ tab, ushort_t* __restrict__ Q) {
  const int h = id & 3, st = (id >> 2) & 63, b = id >> 8;
  const int t = threadIdx.x, si = t & 63, wid = t >> 6;
  const int l15 = t & 15, lg = (t >> 4) & 3;
  const float* cf = coef + b * 320;
  ushort_t* Xt = smem;           // [64][64]
  ushort_t* sQ = smem + 4096;    // [64][128]
  {
    ushort_t pk[8];
#pragma unroll
    for (int j = 0; j < 8; j++) {
      int c = wid * 8 + j;
      float v = y_q[(size_t)(b * 32 + c) * S_TOT + st * 64 + si];
      pk[j] = f2b(v * cf[c] + cf[32 + c]);
    }
    *(s16x8*)((char*)(Xt + si * 64) + ((wid * 16) ^ ((si & 7) << 4))) = *(s16x8*)pk;
  }
  __syncthreads();
  const int d0w = wid * 32;
  f32x4 acc[2][4];
#pragma unroll
  for (int db = 0; db < 2; db++) {
    f32x4 bv;
#pragma unroll
    for (int r = 0; r < 4; r++) bv[r] = q2b2[h * 128 + d0w + db * 16 + lg * 4 + r];
#pragma unroll
    for (int sb = 0; sb < 4; sb++) acc[db][sb] = bv;
  }
  s16x8 wf[2];
#pragma unroll
  for (int db = 0; db < 2; db++)
    wf[db] = *(const s16x8*)(wq2 + (size_t)(h * 128 + d0w + db * 16 + l15) * 32 + lg * 8);
  const int xsw = (lg * 16) ^ ((l15 & 7) << 4);
#pragma unroll
  for (int sb = 0; sb < 4; sb++) {
    s16x8 xf = *(const s16x8*)((const char*)(Xt + (sb * 16 + l15) * 64) + xsw);
#pragma unroll
    for (int db = 0; db < 2; db++)
      acc[db][sb] = __builtin_amdgcn_mfma_f32_16x16x32_bf16(wf[db], xf, acc[db][sb], 0, 0, 0);
  }
  if (wid >= 2) {
#pragma unroll
    for (int db = 0; db < 2; db++)
#pragma unroll
      for (int sb = 0; sb < 4; sb++) {
        int sp = st * 64 + sb * 16 + l15, hi = sp >> 6, wi = sp & 63;
        int dg = d0w + db * 16 + lg * 4;
#pragma unroll
        for (int pr = 0; pr < 2; pr++) {
          float v0 = acc[db][sb][pr * 2], v1 = acc[db][sb][pr * 2 + 1];
          int p = (dg + pr * 2 - 64) >> 1;
          rope_pair_t(v0, v1, p, hi, wi, QSL, tab);
          acc[db][sb][pr * 2] = v0; acc[db][sb][pr * 2 + 1] = v1;
        }
      }
  } else {
#pragma unroll
    for (int db = 0; db < 2; db++)
#pragma unroll
      for (int sb = 0; sb < 4; sb++)
#pragma unroll
        for (int r = 0; r < 4; r++) acc[db][sb][r] *= QSL;
  }
#pragma unroll
  for (int db = 0; db < 2; db++)
#pragma unroll
    for (int sb = 0; sb < 4; sb++) {
      ushort_t pk[4];
#pragma unroll
      for (int r = 0; r < 4; r++) pk[r] = f2b(acc[db][sb][r]);
      int srow = sb * 16 + l15;
      *(s16x4*)((char*)(sQ + srow * 128) + (((d0w + db * 16 + lg * 4) * 2) ^ ((srow & 7) << 4))) =
          *(s16x4*)pk;
    }
  __syncthreads();
  ushort_t* qrow = Q + ((size_t)(b * 4 + h) * S_TOT + st * 64 + si) * 128 + wid * 32;
#pragma unroll
  for (int j = 0; j < 4; j++) {
    s16x8 v = *(const s16x8*)((const char*)(sQ + si * 128) + ((wid * 64 + j * 16) ^ ((si & 7) << 4)));
    *(s16x8*)(qrow + j * 8) = v;
  }
}

__device__ __forceinline__ void lat_body(
    int blk, const float* __restrict__ y_kv, const float* __restrict__ coef,
    const float2* __restrict__ tab, ushort_t* __restrict__ C, ushort_t* __restrict__ VT) {
  const int b = blk >> 6, st = (blk & 63) * 64;
  const int t = threadIdx.x, si = t & 63, g = t >> 6;
  const float* cf = coef + b * 320;
  const int sp = st + si;
  if (g < 2) {
    const int c0 = g * 32;
    float v[32];
#pragma unroll
    for (int j = 0; j < 32; j++) {
      int c = c0 + j;
      v[j] = y_kv[(size_t)(b * 128 + c) * S_TOT + sp] * cf[64 + c] + cf[128 + c];
    }
    const int hi = sp >> 6, wi = sp & 63;
#pragma unroll
    for (int k = 0; k < 16; k++)
      rope_pair_t(v[2 * k], v[2 * k + 1], (c0 >> 1) + k, hi, wi, 1.0f, tab);
    ushort_t pk[32];
#pragma unroll
    for (int j = 0; j < 32; j++) pk[j] = f2b(v[j]);
    ushort_t* crow = C + (size_t)(b * S_TOT + sp) * 128 + 64 + c0;
#pragma unroll
    for (int j4 = 0; j4 < 4; j4++) *(s16x8*)(crow + j4 * 8) = *(s16x8*)(pk + j4 * 8);
  } else {
    const int c0 = (g - 2) * 32;
    ushort_t pk[32];
#pragma unroll
    for (int j = 0; j < 32; j++) {
      int c2 = c0 + j;
      float v = y_kv[(size_t)(b * 128 + 64 + c2) * S_TOT + sp] * cf[192 + c2] + cf[256 + c2];
      ushort_t u = f2b(v);
      pk[j] = u;
      VT[(size_t)(b * 64 + c2) * S_TOT + sp] = u;
    }
    ushort_t* crow = C + (size_t)(b * S_TOT + sp) * 128 + c0;
#pragma unroll
    for (int j4 = 0; j4 < 4; j4++) *(s16x8*)(crow + j4 * 8) = *(s16x8*)(pk + j4 * 8);
  }
}

__global__ __launch_bounds__(256) void k_build(
    const float* __restrict__ y_q, const float* __restrict__ y_kv,
    const float* __restrict__ coef,
    const ushort_t* __restrict__ wq2, const float* __restrict__ q2b2,
    const float2* __restrict__ tab,
    ushort_t* __restrict__ Q, ushort_t* __restrict__ C, ushort_t* __restrict__ VT) {
  __shared__ __align__(16) ushort_t smem[12288];  // 24 KB
  if (blockIdx.x < 512) gq_body(blockIdx.x, smem, y_q, coef, wq2, q2b2, tab, Q);
  else                  lat_body(blockIdx.x - 512, y_kv, coef, tab, C, VT);
}

// ---------------------------------------------------------------------------
// K5: flash attention over shared latent (round-13 structure).
// 32x32 MFMA, QBLK=32/wave, 4 waves; triple-buffered counted-vmcnt pipeline;
// fixed-reference softmax (exp2 direct); P via cvt_pk + permlane32_swap.
// Output UNNORMALIZED (bf16) + per-row l; k_oc divides by (l0+l1).
// grid 512 = 2 half x 8 bh x 32 qblk. LDS 72 KB.
__global__ __launch_bounds__(256, 2) void k_attn(
    const ushort_t* __restrict__ Q, const ushort_t* __restrict__ C,
    const ushort_t* __restrict__ VT, ushort_t* __restrict__ Opart,
    float* __restrict__ lvec) {
  const int bid = blockIdx.x;
  const int bh = bid & 7;                  // XCD swizzle: one bh per XCD
  const int rest = bid >> 3;               // [0,64)
  const int half = rest >> 5, qblk = rest & 31;
  const int kv0 = half * 2048;
  const int tid = threadIdx.x;
  const int wid = tid >> 6, lane = tid & 63;
  const int l31 = lane & 31, hi = lane >> 5;
  const int qbase = qblk * 128 + wid * 32;
  const int b4 = bh >> 2;                  // batch index
  const ushort_t* Qp = Q + (size_t)bh * S_TOT * 128;
  const ushort_t* Kp = C + (size_t)b4 * S_TOT * 128;
  const ushort_t* Vp = VT + (size_t)b4 * 64 * S_TOT;

  __shared__ __align__(16) ushort_t K_lds[3][64][128];  // 48 KB
  __shared__ __align__(16) ushort_t V_lds[3][64][64];   // 24 KB

  s16x8 qf[8];
#pragma unroll
  for (int c = 0; c < 8; c++)
    qf[c] = *(const s16x8*)(Qp + (size_t)(qbase + l31) * 128 + c * 16 + hi * 8);

  f32x16 o0, o1;
#pragma unroll
  for (int r = 0; r < 16; r++) { o0[r] = 0.f; o1[r] = 0.f; }
  float l_s = 0.f;

  const int krow_l = tid >> 4;   // +i*16
  const int kcolb = (tid & 15) * 16;
  const int vrow_l = tid >> 3;   // +i*32
  const int vcolb = (tid & 7) * 16;

#define STAGE(kvb, bufi)                                                          \
  {                                                                               \
    _Pragma("unroll")                                                             \
    for (int i = 0; i < 4; i++) {                                                 \
      int row = i * 16 + krow_l;                                                  \
      int colb = kcolb ^ ((row & 15) << 4);                                       \
      gload16((const char*)(Kp + (size_t)((kvb) + row) * 128) + colb,             \
              (void*)&K_lds[bufi][i * 16 + wid * 4][0]);                          \
    }                                                                             \
    _Pragma("unroll")                                                             \
    for (int i = 0; i < 2; i++) {                                                 \
      int vd = i * 32 + vrow_l;                                                   \
      int colb = vcolb ^ ((vd & 7) << 4);                                         \
      gload16((const char*)(Vp + (size_t)vd * S_TOT + (kvb)) + colb,              \
              (void*)&V_lds[bufi][i * 32 + wid * 8][0]);                          \
    }                                                                             \
  }

  STAGE(kv0, 0);            // 6 loads
  STAGE(kv0 + 64, 1);       // 12 outstanding

  const int kswz = (l31 & 15) << 4;
  const int vswz = (l31 & 7) << 4;
#pragma unroll 1
  for (int t = 0; t < 32; t++) {
    const int buf = t % 3;
    if (t < 31) {
      asm volatile("s_waitcnt vmcnt(6)" ::: "memory");   // own buf-t loads done
    } else {
      asm volatile("s_waitcnt vmcnt(0)" ::: "memory");
    }
    __builtin_amdgcn_sched_barrier(0);
    __builtin_amdgcn_s_barrier();          // publishes everyone's buf-t loads
    __builtin_amdgcn_sched_barrier(0);
    if (t < 30) STAGE(kv0 + (t + 2) * 64, (t + 2) % 3);  // flies for ~2 iters
    f32x16 sc0, sc1;
#pragma unroll
    for (int r = 0; r < 16; r++) { sc0[r] = 0.f; sc1[r] = 0.f; }
    __builtin_amdgcn_s_setprio(1);
#pragma unroll
    for (int c = 0; c < 8; c++) {
      const int off = (c * 32 + hi * 16) ^ kswz;
      s16x8 k0 = *(const s16x8*)((const char*)&K_lds[buf][l31][0] + off);
      s16x8 k1 = *(const s16x8*)((const char*)&K_lds[buf][32 + l31][0] + off);
      sc0 = __builtin_amdgcn_mfma_f32_32x32x16_bf16(k0, qf[c], sc0, 0, 0, 0);
      sc1 = __builtin_amdgcn_mfma_f32_32x32x16_bf16(k1, qf[c], sc1, 0, 0, 0);
    }
    __builtin_amdgcn_s_setprio(0);
    // fixed-reference softmax numerator: P = exp2(s) directly
    float rs = 0.f;
#pragma unroll
    for (int r = 0; r < 16; r++) {
      float p0 = exp2f(sc0[r]);
      float p1 = exp2f(sc1[r]);
      sc0[r] = p0; sc1[r] = p1;
      rs += p0 + p1;
    }
    l_s += rs;
    __builtin_amdgcn_s_setprio(1);
#pragma unroll
    for (int c = 0; c < 4; c++) {
      const f32x16 P = (c < 2) ? sc0 : sc1;
      const int rA = 8 * (c & 1);
      uint_t a0 = cvt_pk_bf16(P[rA + 0], P[rA + 1]);
      uint_t a1 = cvt_pk_bf16(P[rA + 2], P[rA + 3]);
      uint_t b0 = cvt_pk_bf16(P[rA + 4], P[rA + 5]);
      uint_t b1 = cvt_pk_bf16(P[rA + 6], P[rA + 7]);
      asm volatile("v_permlane32_swap_b32 %0, %1" : "+v"(a0), "+v"(b0));
      asm volatile("v_permlane32_swap_b32 %0, %1" : "+v"(a1), "+v"(b1));
      union { uint_t u[4]; s16x8 v; } pf;
      pf.u[0] = a0; pf.u[1] = a1;
      pf.u[2] = b0; pf.u[3] = b1;
      const int voff = (c * 32 + hi * 16) ^ vswz;
      s16x8 v0 = *(const s16x8*)((const char*)&V_lds[buf][l31][0] + voff);
      s16x8 v1 = *(const s16x8*)((const char*)&V_lds[buf][32 + l31][0] + voff);
      o0 = __builtin_amdgcn_mfma_f32_32x32x16_bf16(v0, pf.v, o0, 0, 0, 0);
      o1 = __builtin_amdgcn_mfma_f32_32x32x16_bf16(v1, pf.v, o1, 0, 0, 0);
    }
    __builtin_amdgcn_s_setprio(0);
  }
#undef STAGE
  l_s += __shfl_xor(l_s, 32, 64);
  if (lane < 32)
    lvec[((size_t)(half * 8 + bh) << 12) + qbase + l31] = l_s;
  // O^T -> O epilogue via LDS bounce (reuse K_lds[0]); UNNORMALIZED output
  char* sO = (char*)&K_lds[0][0][0];
#pragma unroll
  for (int vt = 0; vt < 2; vt++) {
#pragma unroll
    for (int r = 0; r < 16; r += 2) {
      float v0 = (vt ? o1[r] : o0[r]);
      float v1 = (vt ? o1[r + 1] : o0[r + 1]);
      uint_t u = cvt_pk_bf16(v0, v1);
      int vd = vt * 32 + (r & 3) + 8 * (r >> 2) + 4 * hi;
      *(uint_t*)(sO + (wid * 32 + l31) * 128 + ((vd * 2) ^ ((l31 & 7) << 4))) = u;
    }
  }
  __syncthreads();
  {
    const int r = tid >> 1, hf = tid & 1;
    const int w = r >> 5, ql = r & 31;
    ushort_t* orow = Opart + ((size_t)(half * 8 + bh) * S_TOT + qblk * 128 + r) * 64 + hf * 32;
#pragma unroll
    for (int j = 0; j < 4; j++) {
      s16x8 v = *(const s16x8*)(sO + (w * 32 + ql) * 128 + ((hf * 64 + j * 16) ^ ((ql & 7) << 4)));
      *(s16x8*)(orow + j * 8) = v;
    }
  }
}

// ---------------------------------------------------------------------------
// K6: out conv (absorbed W_v) + fused combine: X = (O0_raw + O1_raw)/(l0+l1).
__global__ __launch_bounds__(256) void k_oc(
    const ushort_t* __restrict__ Opart, const float* __restrict__ lvec,
    const ushort_t* __restrict__ wout, const float* __restrict__ outb2,
    const float* __restrict__ x, float* __restrict__ out) {
  const int id = blockIdx.x;
  const int cch = id & 1, st32 = (id >> 1) & 127, b = id >> 8;
  const int t = threadIdx.x, wid = t >> 6;
  const int l15 = t & 15, lg = (t >> 4) & 3;
  __shared__ __align__(16) ushort_t Xt[32][256];
  {
    const int s = t & 31, grp = t >> 5;
    const int h = grp >> 1, vd0 = (grp & 1) * 32;
    const int sp = st32 * 32 + s;
    const float l0 = lvec[((size_t)(b * 4 + h) << 12) + sp];
    const float l1 = lvec[((size_t)(8 + b * 4 + h) << 12) + sp];
    const float w = 1.f / (l0 + l1);
    const ushort_t* oa = Opart + ((size_t)(b * 4 + h) * S_TOT + sp) * 64 + vd0;
    const ushort_t* obp = oa + (size_t)8 * S_TOT * 64;
#pragma unroll
    for (int j4 = 0; j4 < 4; j4++) {
      union { s16x8 v; ushort_t u[8]; } av, bv2;
      av.v = *(const s16x8*)(oa + j4 * 8);
      bv2.v = *(const s16x8*)(obp + j4 * 8);
      ushort_t pk[8];
#pragma unroll
      for (int j = 0; j < 8; j++) pk[j] = f2b(w * (b2f(av.u[j]) + b2f(bv2.u[j])));
      *(s16x8*)((char*)&Xt[s][0] + ((grp * 64 + j4 * 16) ^ ((s & 7) << 4))) = *(s16x8*)pk;
    }
  }
  __syncthreads();
  const int c0w = cch * 64 + wid * 16;
  f32x4 acc[2];
  {
    f32x4 bv;
#pragma unroll
    for (int r = 0; r < 4; r++) bv[r] = outb2[c0w + lg * 4 + r];
    acc[0] = bv; acc[1] = bv;
  }
#pragma unroll
  for (int kk = 0; kk < 8; kk++) {
    s16x8 wf = *(const s16x8*)(wout + (size_t)(c0w + l15) * 256 + kk * 32 + lg * 8);
#pragma unroll
    for (int sb = 0; sb < 2; sb++) {
      s16x8 xf = *(const s16x8*)((const char*)&Xt[sb * 16 + l15][0] +
                                 ((kk * 64 + lg * 16) ^ ((l15 & 7) << 4)));
      acc[sb] = __builtin_amdgcn_mfma_f32_16x16x32_bf16(wf, xf, acc[sb], 0, 0, 0);
    }
  }
#pragma unroll
  for (int sb = 0; sb < 2; sb++) {
#pragma unroll
    for (int r = 0; r < 4; r++) {
      int c = c0w + lg * 4 + r;
      int sp = st32 * 32 + sb * 16 + l15;
      size_t idx = (size_t)(b * 128 + c) * S_TOT + sp;
      out[idx] = acc[sb][r] + x[idx];
    }
  }
}

// ---------------------------------------------------------------------------
extern "C" void kernel_launch(void* const* d_in, const int* in_sizes, int n_in,
                              void* d_out, int out_size, void* d_ws, size_t ws_size,
                              hipStream_t stream) {
  const float* x      = (const float*)d_in[0];
  const float* q1_w   = (const float*)d_in[1];
  const float* q1_b   = (const float*)d_in[2];
  const float* q_gn_g = (const float*)d_in[3];
  const float* q_gn_b = (const float*)d_in[4];
  const float* q2_w   = (const float*)d_in[5];
  const float* q2_b   = (const float*)d_in[6];
  const float* kv1_w  = (const float*)d_in[7];
  const float* kv1_b  = (const float*)d_in[8];
  const float* kv_gn_g= (const float*)d_in[9];
  const float* kv_gn_b= (const float*)d_in[10];
  const float* kvn_g  = (const float*)d_in[11];
  const float* kvn_b  = (const float*)d_in[12];
  const float* kvup_w = (const float*)d_in[13];
  const float* kvup_b = (const float*)d_in[14];
  const float* out_w  = (const float*)d_in[15];
  const float* out_b  = (const float*)d_in[16];

  const size_t MB = 1u << 20;
  char* ws = (char*)d_ws;
  float*    y_q   = (float*)(ws);                           // 0..1 MB
  float*    y_kv  = (float*)(ws + 1 * MB);                  // 1..5 MB
  ushort_t* Q     = (ushort_t*)(ws + 5 * MB);               // 5..13 MB
  ushort_t* C     = (ushort_t*)(ws + 13 * MB);              // 13..15 MB (latent+rope)
  ushort_t* VT    = (ushort_t*)(ws + 15 * MB);              // 15..16 MB (latent^T)
  double*   pch   = (double*)(ws + 17 * MB);                // 17..18.25 MB
  double*   SQ    = (double*)(ws + 19 * MB);                // 5 KB
  float*    coef  = (float*)(ws + 19 * MB + 8192);          // 2.5 KB
  ushort_t* wq2   = (ushort_t*)(ws + 19 * MB + 16384);      // 32 KB
  ushort_t* wout  = (ushort_t*)(ws + 19 * MB + 65536);      // 64 KB
  float*    q2b2  = (float*)(ws + 19 * MB + 131072);        // 2 KB
  float*    outb2 = (float*)(ws + 19 * MB + 139264);        // 512 B
  float2*   tab   = (float2*)(ws + 19 * MB + 143360);       // 8 KB rope trig table
  ushort_t* Opart = (ushort_t*)(ws + 20 * MB);              // 20..28 MB
  float*    lvec  = (float*)(ws + 28 * MB);                 // 256 KB
  float*    out   = (float*)d_out;

  k_conv1<<<707, 256, 0, stream>>>(x, q1_w, q1_b, kv1_w, kv1_b, y_q, y_kv, pch,
                                   q2_w, q2_b, kvup_w, kvup_b, out_w, out_b,
                                   wq2, wout, q2b2, outb2);
  k_red  <<<320, 256, 0, stream>>>(pch, SQ);
  k_stats<<<1,   512, 0, stream>>>(SQ, q_gn_g, q_gn_b, kv_gn_g, kv_gn_b, kvn_g, kvn_b,
                                   coef, tab);
  k_build<<<640, 256, 0, stream>>>(y_q, y_kv, coef, wq2, q2b2, tab, Q, C, VT);
  k_attn <<<512, 256, 0, stream>>>(Q, C, VT, Opart, lvec);
  k_oc   <<<512, 256, 0, stream>>>(Opart, lvec, wout, outb2, x, out);
}

// Round 19
// 126.197 us; speedup vs baseline: 1.1709x; 1.1296x over previous
//
#include <hip/hip_runtime.h>

typedef unsigned short ushort_t;
typedef unsigned int uint_t;
typedef __attribute__((ext_vector_type(8))) short s16x8;
typedef __attribute__((ext_vector_type(4))) short s16x4;
typedef __attribute__((ext_vector_type(4))) float f32x4;
typedef __attribute__((ext_vector_type(16))) float f32x16;

#define S_TOT 4096
#define QSCALE 0.08838834764831845f       // 1/sqrt(128)
#define LOG2E 1.4426950408889634f
#define QSL (QSCALE * LOG2E)              // baked into Q -> attn uses exp2
#define L2_10000_D16 0.8304820237218406f  // log2(10000)/16

__device__ __forceinline__ ushort_t f2b(float f) {
  uint_t u = __float_as_uint(f);
  uint_t r = (u + 0x7FFFu + ((u >> 16) & 1u)) >> 16;
  return (ushort_t)r;
}

__device__ __forceinline__ float b2f(ushort_t u) {
  return __uint_as_float((uint_t)u << 16);
}

__device__ __forceinline__ uint_t cvt_pk_bf16(float lo, float hi) {
  uint_t r;
  asm("v_cvt_pk_bf16_f32 %0, %1, %2" : "=v"(r) : "v"(lo), "v"(hi));
  return r;
}

__device__ __forceinline__ void gload16(const void* g, void* l) {
  __builtin_amdgcn_global_load_lds(
      (const __attribute__((address_space(1))) unsigned int*)g,
      (__attribute__((address_space(3))) unsigned int*)l, 16, 0, 0);
}

// table-driven rope pair: tab[src*16+j] = {sin(src*inv_j), cos(src*inv_j)}
__device__ __forceinline__ void rope_pair_t(float& x0, float& x1, int p, int hi, int wi,
                                            float scale, const float2* __restrict__ tab) {
  int j = p >> 1;
  int src = (p & 1) ? wi : hi;
  float2 sc = tab[src * 16 + j];
  float r0 = (x0 * sc.x - x1 * sc.y) * scale;
  float r1 = (x0 * sc.y + x1 * sc.x) * scale;
  x0 = r0; x1 = r1;
}

// ---------------------------------------------------------------------------
// K1: blocks 0..255: conv1 as MFMA GEMM (160 out ch x 32 s, K=128, bf16).
// blocks 256..450: MLA weight ABSORPTION (bf16) (unchanged math).
__global__ __launch_bounds__(256) void k_conv1(
    const float* __restrict__ x, const float* __restrict__ q1_w, const float* __restrict__ q1_b,
    const float* __restrict__ kv1_w, const float* __restrict__ kv1_b,
    float* __restrict__ y_q, float* __restrict__ y_kv,
    const float* __restrict__ q2_w, const float* __restrict__ q2_b,
    const float* __restrict__ kvup_w, const float* __restrict__ kvup_b,
    const float* __restrict__ out_w, const float* __restrict__ out_b,
    ushort_t* __restrict__ wq2, ushort_t* __restrict__ wout,
    float* __restrict__ q2b2, float* __restrict__ outb2) {
  if (blockIdx.x >= 256) {
    int E = (blockIdx.x - 256) * 256 + threadIdx.x;
    if (E < 16384) {            // wq2' (absorbed q2 weights), 512x32
      int oc = E >> 5, r = E & 31;
      int h = oc >> 7, d = oc & 127;
      float val;
      if (d < 64) {
        val = 0.f;
        for (int dd = 0; dd < 64; dd++)
          val += kvup_w[(h * 128 + dd) * 64 + d] * q2_w[(size_t)(h * 128 + dd) * 32 + r];
      } else {
        val = q2_w[(size_t)oc * 32 + r];
      }
      wq2[(size_t)oc * 32 + r] = f2b(val);
    } else if (E < 49152) {     // wout' (absorbed out conv), 128x256
      int e = E - 16384;
      int c = e >> 8, col = e & 255;
      int h = col >> 6, l = col & 63;
      float val = 0.f;
      for (int vd = 0; vd < 64; vd++)
        val += out_w[(size_t)c * 256 + h * 64 + vd] * kvup_w[(h * 128 + 64 + vd) * 64 + l];
      wout[(size_t)c * 256 + col] = f2b(val);
    } else if (E < 49664) {     // q2b'
      int oc = E - 49152;
      int h = oc >> 7, d = oc & 127;
      float val;
      if (d < 64) {
        val = 0.f;
        for (int dd = 0; dd < 64; dd++)
          val += kvup_w[(h * 128 + dd) * 64 + d] * q2_b[h * 128 + dd];
      } else val = q2_b[oc];
      q2b2[oc] = val;
    } else if (E < 49792) {     // outb'
      int c = E - 49664;
      float val = out_b[c];
      for (int j = 0; j < 256; j++) {
        int h = j >> 6, vd = j & 63;
        val += out_w[(size_t)c * 256 + j] * kvup_b[h * 128 + 64 + vd];
      }
      outb2[c] = val;
    }
    return;
  }
  // conv part: grid 256 = B * 128 blocks of 32 s
  const int id = blockIdx.x;
  const int b = id >> 7, blk = id & 127, st = blk * 32;
  const int t = threadIdx.x, wid = t >> 6;
  const int l15 = t & 15, lg = (t >> 4) & 3;
  __shared__ __align__(16) ushort_t Xt[32][128];   // 8 KB, XOR-swizzled rows (256B)
  {
    const int si = t & 31, g = t >> 5;
#pragma unroll
    for (int half = 0; half < 2; half++) {
      ushort_t pk[8];
#pragma unroll
      for (int j = 0; j < 8; j++) {
        int c = g * 16 + half * 8 + j;
        pk[j] = f2b(x[(size_t)(b * 128 + c) * S_TOT + st + si]);
      }
      *(s16x8*)((char*)&Xt[si][0] + ((g * 32 + half * 16) ^ ((si & 15) << 4))) = *(s16x8*)pk;
    }
  }
  __syncthreads();
  // 20 output tiles (10 row-tiles x 2 col-tiles); wave takes 5
#pragma unroll
  for (int k5 = 0; k5 < 5; k5++) {
    const int tt = wid * 5 + k5;
    const int rt = tt >> 1, ct = tt & 1;
    const int oc0 = rt * 16;
    f32x4 acc;
#pragma unroll
    for (int r = 0; r < 4; r++) {
      int oc = oc0 + lg * 4 + r;
      acc[r] = (oc < 32) ? q1_b[oc] : kv1_b[oc - 32];
    }
    const int wrow = oc0 + l15;
    const float4* wr4 = (wrow < 32) ? ((const float4*)q1_w) + (size_t)wrow * 32
                                    : ((const float4*)kv1_w) + (size_t)(wrow - 32) * 32;
    const int xrow = ct * 16 + l15;
    const int xswz = (xrow & 15) << 4;
#pragma unroll
    for (int kk = 0; kk < 4; kk++) {
      float4 wa = wr4[kk * 8 + lg * 2];
      float4 wb = wr4[kk * 8 + lg * 2 + 1];
      ushort_t wp[8];
      wp[0] = f2b(wa.x); wp[1] = f2b(wa.y); wp[2] = f2b(wa.z); wp[3] = f2b(wa.w);
      wp[4] = f2b(wb.x); wp[5] = f2b(wb.y); wp[6] = f2b(wb.z); wp[7] = f2b(wb.w);
      s16x8 wf = *(s16x8*)wp;
      s16x8 xf = *(const s16x8*)((const char*)&Xt[xrow][0] + ((kk * 64 + lg * 16) ^ xswz));
      acc = __builtin_amdgcn_mfma_f32_16x16x32_bf16(wf, xf, acc, 0, 0, 0);
    }
    const int sp = st + ct * 16 + l15;
#pragma unroll
    for (int r = 0; r < 4; r++) {
      int oc = oc0 + lg * 4 + r;
      if (oc < 32) y_q[(size_t)(b * 32 + oc) * S_TOT + sp] = acc[r];
      else         y_kv[(size_t)(b * 128 + oc - 32) * S_TOT + sp] = acc[r];
    }
  }
}

// ---------------------------------------------------------------------------
// K2a: per-channel (sum, sumsq) reduction straight over y rows (coalesced).
// grid 320 = pair (b*160 + c). f64 accumulation.
__global__ __launch_bounds__(256) void k_red(
    const float* __restrict__ y_q, const float* __restrict__ y_kv,
    double* __restrict__ SQ) {
  const int pair = blockIdx.x, tid = threadIdx.x;
  const int lane = tid & 63, wid = tid >> 6;
  const int b = pair / 160, c = pair % 160;
  const float* row = (c < 32) ? y_q + ((size_t)(b * 32 + c) << 12)
                              : y_kv + ((size_t)(b * 128 + c - 32) << 12);
  const float4* r4 = (const float4*)row;
  double s = 0, q = 0;
#pragma unroll
  for (int j = 0; j < 4; j++) {
    float4 v = r4[tid * 4 + j];
    s += (double)v.x + (double)v.y + (double)v.z + (double)v.w;
    q += (double)v.x * v.x + (double)v.y * v.y + (double)v.z * v.z + (double)v.w * v.w;
  }
#pragma unroll
  for (int o = 1; o < 64; o <<= 1) { s += __shfl_xor(s, o, 64); q += __shfl_xor(q, o, 64); }
  __shared__ double red[4][2];
  if (lane == 0) { red[wid][0] = s; red[wid][1] = q; }
  __syncthreads();
  if (tid == 0) {
    SQ[pair * 2]     = red[0][0] + red[1][0] + red[2][0] + red[3][0];
    SQ[pair * 2 + 1] = red[0][1] + red[1][1] + red[2][1] + red[3][1];
  }
}

// K2b: compose group-norms into per-channel affine coefs + fill rope trig
// table: tab[src*16+j] = {sin(src*inv_j), cos(src*inv_j)}, src in 0..63.
__global__ __launch_bounds__(512) void k_stats(
    const double* __restrict__ SQ,
    const float* __restrict__ qg, const float* __restrict__ qb,
    const float* __restrict__ kvg, const float* __restrict__ kvb,
    const float* __restrict__ kng, const float* __restrict__ knb,
    float* __restrict__ coef, float2* __restrict__ tab) {
  __shared__ double Sh[2][160], Qh[2][160];
  const int tid = threadIdx.x;
  for (int i = tid; i < 1024; i += 512) {
    int src = i >> 4, j = i & 15;
    float inv = exp2f(-(float)j * L2_10000_D16);
    float ang = (float)src * inv;
    tab[i] = make_float2(sinf(ang), cosf(ang));
  }
  if (tid < 320) {
    int b = tid / 160, c = tid % 160;
    Sh[b][c] = SQ[tid * 2]; Qh[b][c] = SQ[tid * 2 + 1];
  }
  __syncthreads();
  if (tid < 2) {
    int b = tid;
    float* cf = coef + b * 320;
    const double NS = 4096.0;
    double muq = 0, m2q = 0;
    for (int c = 0; c < 32; c++) { muq += Sh[b][c]; m2q += Qh[b][c]; }
    muq /= (32.0 * NS); m2q /= (32.0 * NS);
    double rstdq = 1.0 / sqrt(m2q - muq * muq + 1e-5);
    for (int c = 0; c < 32; c++) {
      double A = rstdq * (double)qg[c];
      cf[c] = (float)A; cf[32 + c] = (float)((double)qb[c] - muq * A);
    }
    double mukv = 0, m2kv = 0;
    for (int c = 0; c < 128; c++) { mukv += Sh[b][32 + c]; m2kv += Qh[b][32 + c]; }
    mukv /= (128.0 * NS); m2kv /= (128.0 * NS);
    double rstdkv = 1.0 / sqrt(m2kv - mukv * mukv + 1e-5);
    for (int c = 0; c < 64; c++) {
      double A = rstdkv * (double)kvg[c];
      cf[64 + c] = (float)A; cf[128 + c] = (float)((double)kvb[c] - mukv * A);
    }
    double mu2 = 0, m22 = 0;
    for (int c2 = 0; c2 < 64; c2++) {
      int c = 64 + c2;
      double a = rstdkv * (double)kvg[c], bb = (double)kvb[c] - mukv * a;
      double Ec = Sh[b][32 + c] / NS, M2c = Qh[b][32 + c] / NS;
      mu2 += a * Ec + bb;
      m22 += a * a * M2c + 2.0 * a * bb * Ec + bb * bb;
    }
    mu2 /= 64.0; m22 /= 64.0;
    double rstd2 = 1.0 / sqrt(m22 - mu2 * mu2 + 1e-5);
    for (int c2 = 0; c2 < 64; c2++) {
      int c = 64 + c2;
      double a = rstdkv * (double)kvg[c], bb = (double)kvb[c] - mukv * a;
      cf[192 + c2] = (float)(a * rstd2 * (double)kng[c2]);
      cf[256 + c2] = (float)((bb - mu2) * rstd2 * (double)kng[c2] + (double)knb[c2]);
    }
  }
}

// ---------------------------------------------------------------------------
// K3 merged: blocks 0..511 = Q build (MFMA GEMM, absorbed weights);
// blocks 512..639 = latent build. Shared static LDS 24 KB. Table-driven rope.
__device__ __forceinline__ void gq_body(
    int id, ushort_t* smem,
    const float* __restrict__ y_q, const float* __restrict__ coef,
    const ushort_t* __restrict__ wq2, const float* __restrict__ q2b2,
    const float2* __restrict__ tab, ushort_t* __restrict__ Q) {
  const int h = id & 3, st = (id >> 2) & 63, b = id >> 8;
  const int t = threadIdx.x, si = t & 63, wid = t >> 6;
  const int l15 = t & 15, lg = (t >> 4) & 3;
  const float* cf = coef + b * 320;
  ushort_t* Xt = smem;           // [64][64]
  ushort_t* sQ = smem + 4096;    // [64][128]
  {
    ushort_t pk[8];
#pragma unroll
    for (int j = 0; j < 8; j++) {
      int c = wid * 8 + j;
      float v = y_q[(size_t)(b * 32 + c) * S_TOT + st * 64 + si];
      pk[j] = f2b(v * cf[c] + cf[32 + c]);
    }
    *(s16x8*)((char*)(Xt + si * 64) + ((wid * 16) ^ ((si & 7) << 4))) = *(s16x8*)pk;
  }
  __syncthreads();
  const int d0w = wid * 32;
  f32x4 acc[2][4];
#pragma unroll
  for (int db = 0; db < 2; db++) {
    f32x4 bv;
#pragma unroll
    for (int r = 0; r < 4; r++) bv[r] = q2b2[h * 128 + d0w + db * 16 + lg * 4 + r];
#pragma unroll
    for (int sb = 0; sb < 4; sb++) acc[db][sb] = bv;
  }
  s16x8 wf[2];
#pragma unroll
  for (int db = 0; db < 2; db++)
    wf[db] = *(const s16x8*)(wq2 + (size_t)(h * 128 + d0w + db * 16 + l15) * 32 + lg * 8);
  const int xsw = (lg * 16) ^ ((l15 & 7) << 4);
#pragma unroll
  for (int sb = 0; sb < 4; sb++) {
    s16x8 xf = *(const s16x8*)((const char*)(Xt + (sb * 16 + l15) * 64) + xsw);
#pragma unroll
    for (int db = 0; db < 2; db++)
      acc[db][sb] = __builtin_amdgcn_mfma_f32_16x16x32_bf16(wf[db], xf, acc[db][sb], 0, 0, 0);
  }
  if (wid >= 2) {
#pragma unroll
    for (int db = 0; db < 2; db++)
#pragma unroll
      for (int sb = 0; sb < 4; sb++) {
        int sp = st * 64 + sb * 16 + l15, hi = sp >> 6, wi = sp & 63;
        int dg = d0w + db * 16 + lg * 4;
#pragma unroll
        for (int pr = 0; pr < 2; pr++) {
          float v0 = acc[db][sb][pr * 2], v1 = acc[db][sb][pr * 2 + 1];
          int p = (dg + pr * 2 - 64) >> 1;
          rope_pair_t(v0, v1, p, hi, wi, QSL, tab);
          acc[db][sb][pr * 2] = v0; acc[db][sb][pr * 2 + 1] = v1;
        }
      }
  } else {
#pragma unroll
    for (int db = 0; db < 2; db++)
#pragma unroll
      for (int sb = 0; sb < 4; sb++)
#pragma unroll
        for (int r = 0; r < 4; r++) acc[db][sb][r] *= QSL;
  }
#pragma unroll
  for (int db = 0; db < 2; db++)
#pragma unroll
    for (int sb = 0; sb < 4; sb++) {
      ushort_t pk[4];
#pragma unroll
      for (int r = 0; r < 4; r++) pk[r] = f2b(acc[db][sb][r]);
      int srow = sb * 16 + l15;
      *(s16x4*)((char*)(sQ + srow * 128) + (((d0w + db * 16 + lg * 4) * 2) ^ ((srow & 7) << 4))) =
          *(s16x4*)pk;
    }
  __syncthreads();
  ushort_t* qrow = Q + ((size_t)(b * 4 + h) * S_TOT + st * 64 + si) * 128 + wid * 32;
#pragma unroll
  for (int j = 0; j < 4; j++) {
    s16x8 v = *(const s16x8*)((const char*)(sQ + si * 128) + ((wid * 64 + j * 16) ^ ((si & 7) << 4)));
    *(s16x8*)(qrow + j * 8) = v;
  }
}

__device__ __forceinline__ void lat_body(
    int blk, const float* __restrict__ y_kv, const float* __restrict__ coef,
    const float2* __restrict__ tab, ushort_t* __restrict__ C, ushort_t* __restrict__ VT) {
  const int b = blk >> 6, st = (blk & 63) * 64;
  const int t = threadIdx.x, si = t & 63, g = t >> 6;
  const float* cf = coef + b * 320;
  const int sp = st + si;
  if (g < 2) {
    const int c0 = g * 32;
    float v[32];
#pragma unroll
    for (int j = 0; j < 32; j++) {
      int c = c0 + j;
      v[j] = y_kv[(size_t)(b * 128 + c) * S_TOT + sp] * cf[64 + c] + cf[128 + c];
    }
    const int hi = sp >> 6, wi = sp & 63;
#pragma unroll
    for (int k = 0; k < 16; k++)
      rope_pair_t(v[2 * k], v[2 * k + 1], (c0 >> 1) + k, hi, wi, 1.0f, tab);
    ushort_t pk[32];
#pragma unroll
    for (int j = 0; j < 32; j++) pk[j] = f2b(v[j]);
    ushort_t* crow = C + (size_t)(b * S_TOT + sp) * 128 + 64 + c0;
#pragma unroll
    for (int j4 = 0; j4 < 4; j4++) *(s16x8*)(crow + j4 * 8) = *(s16x8*)(pk + j4 * 8);
  } else {
    const int c0 = (g - 2) * 32;
    ushort_t pk[32];
#pragma unroll
    for (int j = 0; j < 32; j++) {
      int c2 = c0 + j;
      float v = y_kv[(size_t)(b * 128 + 64 + c2) * S_TOT + sp] * cf[192 + c2] + cf[256 + c2];
      ushort_t u = f2b(v);
      pk[j] = u;
      VT[(size_t)(b * 64 + c2) * S_TOT + sp] = u;
    }
    ushort_t* crow = C + (size_t)(b * S_TOT + sp) * 128 + c0;
#pragma unroll
    for (int j4 = 0; j4 < 4; j4++) *(s16x8*)(crow + j4 * 8) = *(s16x8*)(pk + j4 * 8);
  }
}

__global__ __launch_bounds__(256) void k_build(
    const float* __restrict__ y_q, const float* __restrict__ y_kv,
    const float* __restrict__ coef,
    const ushort_t* __restrict__ wq2, const float* __restrict__ q2b2,
    const float2* __restrict__ tab,
    ushort_t* __restrict__ Q, ushort_t* __restrict__ C, ushort_t* __restrict__ VT) {
  __shared__ __align__(16) ushort_t smem[12288];  // 24 KB
  if (blockIdx.x < 512) gq_body(blockIdx.x, smem, y_q, coef, wq2, q2b2, tab, Q);
  else                  lat_body(blockIdx.x - 512, y_kv, coef, tab, C, VT);
}

// ---------------------------------------------------------------------------
// K5: flash attention over shared latent (round-13 structure).
// 32x32 MFMA, QBLK=32/wave, 4 waves; triple-buffered counted-vmcnt pipeline;
// fixed-reference softmax (exp2 direct); P via cvt_pk + permlane32_swap.
// Output UNNORMALIZED (bf16) + per-row l; k_oc divides by (l0+l1).
// grid 512 = 2 half x 8 bh x 32 qblk. LDS 72 KB.
__global__ __launch_bounds__(256, 2) void k_attn(
    const ushort_t* __restrict__ Q, const ushort_t* __restrict__ C,
    const ushort_t* __restrict__ VT, ushort_t* __restrict__ Opart,
    float* __restrict__ lvec) {
  const int bid = blockIdx.x;
  const int bh = bid & 7;                  // XCD swizzle: one bh per XCD
  const int rest = bid >> 3;               // [0,64)
  const int half = rest >> 5, qblk = rest & 31;
  const int kv0 = half * 2048;
  const int tid = threadIdx.x;
  const int wid = tid >> 6, lane = tid & 63;
  const int l31 = lane & 31, hi = lane >> 5;
  const int qbase = qblk * 128 + wid * 32;
  const int b4 = bh >> 2;                  // batch index
  const ushort_t* Qp = Q + (size_t)bh * S_TOT * 128;
  const ushort_t* Kp = C + (size_t)b4 * S_TOT * 128;
  const ushort_t* Vp = VT + (size_t)b4 * 64 * S_TOT;

  __shared__ __align__(16) ushort_t K_lds[3][64][128];  // 48 KB
  __shared__ __align__(16) ushort_t V_lds[3][64][64];   // 24 KB

  s16x8 qf[8];
#pragma unroll
  for (int c = 0; c < 8; c++)
    qf[c] = *(const s16x8*)(Qp + (size_t)(qbase + l31) * 128 + c * 16 + hi * 8);

  f32x16 o0, o1;
#pragma unroll
  for (int r = 0; r < 16; r++) { o0[r] = 0.f; o1[r] = 0.f; }
  float l_s = 0.f;

  const int krow_l = tid >> 4;   // +i*16
  const int kcolb = (tid & 15) * 16;
  const int vrow_l = tid >> 3;   // +i*32
  const int vcolb = (tid & 7) * 16;

#define STAGE(kvb, bufi)                                                          \
  {                                                                               \
    _Pragma("unroll")                                                             \
    for (int i = 0; i < 4; i++) {                                                 \
      int row = i * 16 + krow_l;                                                  \
      int colb = kcolb ^ ((row & 15) << 4);                                       \
      gload16((const char*)(Kp + (size_t)((kvb) + row) * 128) + colb,             \
              (void*)&K_lds[bufi][i * 16 + wid * 4][0]);                          \
    }                                                                             \
    _Pragma("unroll")                                                             \
    for (int i = 0; i < 2; i++) {                                                 \
      int vd = i * 32 + vrow_l;                                                   \
      int colb = vcolb ^ ((vd & 7) << 4);                                         \
      gload16((const char*)(Vp + (size_t)vd * S_TOT + (kvb)) + colb,              \
              (void*)&V_lds[bufi][i * 32 + wid * 8][0]);                          \
    }                                                                             \
  }

  STAGE(kv0, 0);            // 6 loads
  STAGE(kv0 + 64, 1);       // 12 outstanding

  const int kswz = (l31 & 15) << 4;
  const int vswz = (l31 & 7) << 4;
#pragma unroll 1
  for (int t = 0; t < 32; t++) {
    const int buf = t % 3;
    if (t < 31) {
      asm volatile("s_waitcnt vmcnt(6)" ::: "memory");   // own buf-t loads done
    } else {
      asm volatile("s_waitcnt vmcnt(0)" ::: "memory");
    }
    __builtin_amdgcn_sched_barrier(0);
    __builtin_amdgcn_s_barrier();          // publishes everyone's buf-t loads
    __builtin_amdgcn_sched_barrier(0);
    if (t < 30) STAGE(kv0 + (t + 2) * 64, (t + 2) % 3);  // flies for ~2 iters
    f32x16 sc0, sc1;
#pragma unroll
    for (int r = 0; r < 16; r++) { sc0[r] = 0.f; sc1[r] = 0.f; }
    __builtin_amdgcn_s_setprio(1);
#pragma unroll
    for (int c = 0; c < 8; c++) {
      const int off = (c * 32 + hi * 16) ^ kswz;
      s16x8 k0 = *(const s16x8*)((const char*)&K_lds[buf][l31][0] + off);
      s16x8 k1 = *(const s16x8*)((const char*)&K_lds[buf][32 + l31][0] + off);
      sc0 = __builtin_amdgcn_mfma_f32_32x32x16_bf16(k0, qf[c], sc0, 0, 0, 0);
      sc1 = __builtin_amdgcn_mfma_f32_32x32x16_bf16(k1, qf[c], sc1, 0, 0, 0);
    }
    __builtin_amdgcn_s_setprio(0);
    // fixed-reference softmax numerator: P = exp2(s) directly
    float rs = 0.f;
#pragma unroll
    for (int r = 0; r < 16; r++) {
      float p0 = exp2f(sc0[r]);
      float p1 = exp2f(sc1[r]);
      sc0[r] = p0; sc1[r] = p1;
      rs += p0 + p1;
    }
    l_s += rs;
    __builtin_amdgcn_s_setprio(1);
#pragma unroll
    for (int c = 0; c < 4; c++) {
      const f32x16 P = (c < 2) ? sc0 : sc1;
      const int rA = 8 * (c & 1);
      uint_t a0 = cvt_pk_bf16(P[rA + 0], P[rA + 1]);
      uint_t a1 = cvt_pk_bf16(P[rA + 2], P[rA + 3]);
      uint_t b0 = cvt_pk_bf16(P[rA + 4], P[rA + 5]);
      uint_t b1 = cvt_pk_bf16(P[rA + 6], P[rA + 7]);
      asm volatile("v_permlane32_swap_b32 %0, %1" : "+v"(a0), "+v"(b0));
      asm volatile("v_permlane32_swap_b32 %0, %1" : "+v"(a1), "+v"(b1));
      union { uint_t u[4]; s16x8 v; } pf;
      pf.u[0] = a0; pf.u[1] = a1;
      pf.u[2] = b0; pf.u[3] = b1;
      const int voff = (c * 32 + hi * 16) ^ vswz;
      s16x8 v0 = *(const s16x8*)((const char*)&V_lds[buf][l31][0] + voff);
      s16x8 v1 = *(const s16x8*)((const char*)&V_lds[buf][32 + l31][0] + voff);
      o0 = __builtin_amdgcn_mfma_f32_32x32x16_bf16(v0, pf.v, o0, 0, 0, 0);
      o1 = __builtin_amdgcn_mfma_f32_32x32x16_bf16(v1, pf.v, o1, 0, 0, 0);
    }
    __builtin_amdgcn_s_setprio(0);
  }
#undef STAGE
  l_s += __shfl_xor(l_s, 32, 64);
  if (lane < 32)
    lvec[((size_t)(half * 8 + bh) << 12) + qbase + l31] = l_s;
  // O^T -> O epilogue via LDS bounce (reuse K_lds[0]); UNNORMALIZED output
  char* sO = (char*)&K_lds[0][0][0];
#pragma unroll
  for (int vt = 0; vt < 2; vt++) {
#pragma unroll
    for (int r = 0; r < 16; r += 2) {
      float v0 = (vt ? o1[r] : o0[r]);
      float v1 = (vt ? o1[r + 1] : o0[r + 1]);
      uint_t u = cvt_pk_bf16(v0, v1);
      int vd = vt * 32 + (r & 3) + 8 * (r >> 2) + 4 * hi;
      *(uint_t*)(sO + (wid * 32 + l31) * 128 + ((vd * 2) ^ ((l31 & 7) << 4))) = u;
    }
  }
  __syncthreads();
  {
    const int r = tid >> 1, hf = tid & 1;
    const int w = r >> 5, ql = r & 31;
    ushort_t* orow = Opart + ((size_t)(half * 8 + bh) * S_TOT + qblk * 128 + r) * 64 + hf * 32;
#pragma unroll
    for (int j = 0; j < 4; j++) {
      s16x8 v = *(const s16x8*)(sO + (w * 32 + ql) * 128 + ((hf * 64 + j * 16) ^ ((ql & 7) << 4)));
      *(s16x8*)(orow + j * 8) = v;
    }
  }
}

// ---------------------------------------------------------------------------
// K6: out conv (absorbed W_v) + fused combine: X = (O0_raw + O1_raw)/(l0+l1).
__global__ __launch_bounds__(256) void k_oc(
    const ushort_t* __restrict__ Opart, const float* __restrict__ lvec,
    const ushort_t* __restrict__ wout, const float* __restrict__ outb2,
    const float* __restrict__ x, float* __restrict__ out) {
  const int id = blockIdx.x;
  const int cch = id & 1, st32 = (id >> 1) & 127, b = id >> 8;
  const int t = threadIdx.x, wid = t >> 6;
  const int l15 = t & 15, lg = (t >> 4) & 3;
  __shared__ __align__(16) ushort_t Xt[32][256];
  {
    const int s = t & 31, grp = t >> 5;
    const int h = grp >> 1, vd0 = (grp & 1) * 32;
    const int sp = st32 * 32 + s;
    const float l0 = lvec[((size_t)(b * 4 + h) << 12) + sp];
    const float l1 = lvec[((size_t)(8 + b * 4 + h) << 12) + sp];
    const float w = 1.f / (l0 + l1);
    const ushort_t* oa = Opart + ((size_t)(b * 4 + h) * S_TOT + sp) * 64 + vd0;
    const ushort_t* obp = oa + (size_t)8 * S_TOT * 64;
#pragma unroll
    for (int j4 = 0; j4 < 4; j4++) {
      union { s16x8 v; ushort_t u[8]; } av, bv2;
      av.v = *(const s16x8*)(oa + j4 * 8);
      bv2.v = *(const s16x8*)(obp + j4 * 8);
      ushort_t pk[8];
#pragma unroll
      for (int j = 0; j < 8; j++) pk[j] = f2b(w * (b2f(av.u[j]) + b2f(bv2.u[j])));
      *(s16x8*)((char*)&Xt[s][0] + ((grp * 64 + j4 * 16) ^ ((s & 7) << 4))) = *(s16x8*)pk;
    }
  }
  __syncthreads();
  const int c0w = cch * 64 + wid * 16;
  f32x4 acc[2];
  {
    f32x4 bv;
#pragma unroll
    for (int r = 0; r < 4; r++) bv[r] = outb2[c0w + lg * 4 + r];
    acc[0] = bv; acc[1] = bv;
  }
#pragma unroll
  for (int kk = 0; kk < 8; kk++) {
    s16x8 wf = *(const s16x8*)(wout + (size_t)(c0w + l15) * 256 + kk * 32 + lg * 8);
#pragma unroll
    for (int sb = 0; sb < 2; sb++) {
      s16x8 xf = *(const s16x8*)((const char*)&Xt[sb * 16 + l15][0] +
                                 ((kk * 64 + lg * 16) ^ ((l15 & 7) << 4)));
      acc[sb] = __builtin_amdgcn_mfma_f32_16x16x32_bf16(wf, xf, acc[sb], 0, 0, 0);
    }
  }
#pragma unroll
  for (int sb = 0; sb < 2; sb++) {
#pragma unroll
    for (int r = 0; r < 4; r++) {
      int c = c0w + lg * 4 + r;
      int sp = st32 * 32 + sb * 16 + l15;
      size_t idx = (size_t)(b * 128 + c) * S_TOT + sp;
      out[idx] = acc[sb][r] + x[idx];
    }
  }
}

// ---------------------------------------------------------------------------
extern "C" void kernel_launch(void* const* d_in, const int* in_sizes, int n_in,
                              void* d_out, int out_size, void* d_ws, size_t ws_size,
                              hipStream_t stream) {
  const float* x      = (const float*)d_in[0];
  const float* q1_w   = (const float*)d_in[1];
  const float* q1_b   = (const float*)d_in[2];
  const float* q_gn_g = (const float*)d_in[3];
  const float* q_gn_b = (const float*)d_in[4];
  const float* q2_w   = (const float*)d_in[5];
  const float* q2_b   = (const float*)d_in[6];
  const float* kv1_w  = (const float*)d_in[7];
  const float* kv1_b  = (const float*)d_in[8];
  const float* kv_gn_g= (const float*)d_in[9];
  const float* kv_gn_b= (const float*)d_in[10];
  const float* kvn_g  = (const float*)d_in[11];
  const float* kvn_b  = (const float*)d_in[12];
  const float* kvup_w = (const float*)d_in[13];
  const float* kvup_b = (const float*)d_in[14];
  const float* out_w  = (const float*)d_in[15];
  const float* out_b  = (const float*)d_in[16];

  const size_t MB = 1u << 20;
  char* ws = (char*)d_ws;
  float*    y_q   = (float*)(ws);                           // 0..1 MB
  float*    y_kv  = (float*)(ws + 1 * MB);                  // 1..5 MB
  ushort_t* Q     = (ushort_t*)(ws + 5 * MB);               // 5..13 MB
  ushort_t* C     = (ushort_t*)(ws + 13 * MB);              // 13..15 MB (latent+rope)
  ushort_t* VT    = (ushort_t*)(ws + 15 * MB);              // 15..16 MB (latent^T)
  double*   SQ    = (double*)(ws + 19 * MB);                // 5 KB
  float*    coef  = (float*)(ws + 19 * MB + 8192);          // 2.5 KB
  ushort_t* wq2   = (ushort_t*)(ws + 19 * MB + 16384);      // 32 KB
  ushort_t* wout  = (ushort_t*)(ws + 19 * MB + 65536);      // 64 KB
  float*    q2b2  = (float*)(ws + 19 * MB + 131072);        // 2 KB
  float*    outb2 = (float*)(ws + 19 * MB + 139264);        // 512 B
  float2*   tab   = (float2*)(ws + 19 * MB + 143360);       // 8 KB rope trig table
  ushort_t* Opart = (ushort_t*)(ws + 20 * MB);              // 20..28 MB
  float*    lvec  = (float*)(ws + 28 * MB);                 // 256 KB
  float*    out   = (float*)d_out;

  k_conv1<<<451, 256, 0, stream>>>(x, q1_w, q1_b, kv1_w, kv1_b, y_q, y_kv,
                                   q2_w, q2_b, kvup_w, kvup_b, out_w, out_b,
                                   wq2, wout, q2b2, outb2);
  k_red  <<<320, 256, 0, stream>>>(y_q, y_kv, SQ);
  k_stats<<<1,   512, 0, stream>>>(SQ, q_gn_g, q_gn_b, kv_gn_g, kv_gn_b, kvn_g, kvn_b,
                                   coef, tab);
  k_build<<<640, 256, 0, stream>>>(y_q, y_kv, coef, wq2, q2b2, tab, Q, C, VT);
  k_attn <<<512, 256, 0, stream>>>(Q, C, VT, Opart, lvec);
  k_oc   <<<512, 256, 0, stream>>>(Opart, lvec, wout, outb2, x, out);
}

// Round 20
// 124.455 us; speedup vs baseline: 1.1873x; 1.0140x over previous
//
#include <hip/hip_runtime.h>

typedef unsigned short ushort_t;
typedef unsigned int uint_t;
typedef __attribute__((ext_vector_type(8))) short s16x8;
typedef __attribute__((ext_vector_type(4))) short s16x4;
typedef __attribute__((ext_vector_type(4))) float f32x4;
typedef __attribute__((ext_vector_type(16))) float f32x16;

#define S_TOT 4096
#define QSCALE 0.08838834764831845f       // 1/sqrt(128)
#define LOG2E 1.4426950408889634f
#define QSL (QSCALE * LOG2E)              // baked into Q -> attn uses exp2
#define L2_10000_D16 0.8304820237218406f  // log2(10000)/16

__device__ __forceinline__ ushort_t f2b(float f) {
  uint_t u = __float_as_uint(f);
  uint_t r = (u + 0x7FFFu + ((u >> 16) & 1u)) >> 16;
  return (ushort_t)r;
}

__device__ __forceinline__ float b2f(ushort_t u) {
  return __uint_as_float((uint_t)u << 16);
}

__device__ __forceinline__ uint_t cvt_pk_bf16(float lo, float hi) {
  uint_t r;
  asm("v_cvt_pk_bf16_f32 %0, %1, %2" : "=v"(r) : "v"(lo), "v"(hi));
  return r;
}

__device__ __forceinline__ void gload16(const void* g, void* l) {
  __builtin_amdgcn_global_load_lds(
      (const __attribute__((address_space(1))) unsigned int*)g,
      (__attribute__((address_space(3))) unsigned int*)l, 16, 0, 0);
}

// table-driven rope pair: tab[src*16+j] = {sin(src*inv_j), cos(src*inv_j)}
__device__ __forceinline__ void rope_pair_t(float& x0, float& x1, int p, int hi, int wi,
                                            float scale, const float2* __restrict__ tab) {
  int j = p >> 1;
  int src = (p & 1) ? wi : hi;
  float2 sc = tab[src * 16 + j];
  float r0 = (x0 * sc.x - x1 * sc.y) * scale;
  float r1 = (x0 * sc.y + x1 * sc.x) * scale;
  x0 = r0; x1 = r1;
}

// ---------------------------------------------------------------------------
// K1: blocks 0..255: conv1 as MFMA GEMM (160 out ch x 32 s, K=128, bf16).
// blocks 256..450: MLA weight ABSORPTION (bf16).
__global__ __launch_bounds__(256) void k_conv1(
    const float* __restrict__ x, const float* __restrict__ q1_w, const float* __restrict__ q1_b,
    const float* __restrict__ kv1_w, const float* __restrict__ kv1_b,
    float* __restrict__ y_q, float* __restrict__ y_kv,
    const float* __restrict__ q2_w, const float* __restrict__ q2_b,
    const float* __restrict__ kvup_w, const float* __restrict__ kvup_b,
    const float* __restrict__ out_w, const float* __restrict__ out_b,
    ushort_t* __restrict__ wq2, ushort_t* __restrict__ wout,
    float* __restrict__ q2b2, float* __restrict__ outb2) {
  if (blockIdx.x >= 256) {
    int E = (blockIdx.x - 256) * 256 + threadIdx.x;
    if (E < 16384) {            // wq2' (absorbed q2 weights), 512x32
      int oc = E >> 5, r = E & 31;
      int h = oc >> 7, d = oc & 127;
      float val;
      if (d < 64) {
        val = 0.f;
        for (int dd = 0; dd < 64; dd++)
          val += kvup_w[(h * 128 + dd) * 64 + d] * q2_w[(size_t)(h * 128 + dd) * 32 + r];
      } else {
        val = q2_w[(size_t)oc * 32 + r];
      }
      wq2[(size_t)oc * 32 + r] = f2b(val);
    } else if (E < 49152) {     // wout' (absorbed out conv), 128x256
      int e = E - 16384;
      int c = e >> 8, col = e & 255;
      int h = col >> 6, l = col & 63;
      float val = 0.f;
      for (int vd = 0; vd < 64; vd++)
        val += out_w[(size_t)c * 256 + h * 64 + vd] * kvup_w[(h * 128 + 64 + vd) * 64 + l];
      wout[(size_t)c * 256 + col] = f2b(val);
    } else if (E < 49664) {     // q2b'
      int oc = E - 49152;
      int h = oc >> 7, d = oc & 127;
      float val;
      if (d < 64) {
        val = 0.f;
        for (int dd = 0; dd < 64; dd++)
          val += kvup_w[(h * 128 + dd) * 64 + d] * q2_b[h * 128 + dd];
      } else val = q2_b[oc];
      q2b2[oc] = val;
    } else if (E < 49792) {     // outb'
      int c = E - 49664;
      float val = out_b[c];
      for (int j = 0; j < 256; j++) {
        int h = j >> 6, vd = j & 63;
        val += out_w[(size_t)c * 256 + j] * kvup_b[h * 128 + 64 + vd];
      }
      outb2[c] = val;
    }
    return;
  }
  // conv part: grid 256 = B * 128 blocks of 32 s
  const int id = blockIdx.x;
  const int b = id >> 7, blk = id & 127, st = blk * 32;
  const int t = threadIdx.x, wid = t >> 6;
  const int l15 = t & 15, lg = (t >> 4) & 3;
  __shared__ __align__(16) ushort_t Xt[32][128];   // 8 KB, XOR-swizzled rows (256B)
  {
    const int si = t & 31, g = t >> 5;
#pragma unroll
    for (int half = 0; half < 2; half++) {
      ushort_t pk[8];
#pragma unroll
      for (int j = 0; j < 8; j++) {
        int c = g * 16 + half * 8 + j;
        pk[j] = f2b(x[(size_t)(b * 128 + c) * S_TOT + st + si]);
      }
      *(s16x8*)((char*)&Xt[si][0] + ((g * 32 + half * 16) ^ ((si & 15) << 4))) = *(s16x8*)pk;
    }
  }
  __syncthreads();
#pragma unroll
  for (int k5 = 0; k5 < 5; k5++) {
    const int tt = wid * 5 + k5;
    const int rt = tt >> 1, ct = tt & 1;
    const int oc0 = rt * 16;
    f32x4 acc;
#pragma unroll
    for (int r = 0; r < 4; r++) {
      int oc = oc0 + lg * 4 + r;
      acc[r] = (oc < 32) ? q1_b[oc] : kv1_b[oc - 32];
    }
    const int wrow = oc0 + l15;
    const float4* wr4 = (wrow < 32) ? ((const float4*)q1_w) + (size_t)wrow * 32
                                    : ((const float4*)kv1_w) + (size_t)(wrow - 32) * 32;
    const int xrow = ct * 16 + l15;
    const int xswz = (xrow & 15) << 4;
#pragma unroll
    for (int kk = 0; kk < 4; kk++) {
      float4 wa = wr4[kk * 8 + lg * 2];
      float4 wb = wr4[kk * 8 + lg * 2 + 1];
      ushort_t wp[8];
      wp[0] = f2b(wa.x); wp[1] = f2b(wa.y); wp[2] = f2b(wa.z); wp[3] = f2b(wa.w);
      wp[4] = f2b(wb.x); wp[5] = f2b(wb.y); wp[6] = f2b(wb.z); wp[7] = f2b(wb.w);
      s16x8 wf = *(s16x8*)wp;
      s16x8 xf = *(const s16x8*)((const char*)&Xt[xrow][0] + ((kk * 64 + lg * 16) ^ xswz));
      acc = __builtin_amdgcn_mfma_f32_16x16x32_bf16(wf, xf, acc, 0, 0, 0);
    }
    const int sp = st + ct * 16 + l15;
#pragma unroll
    for (int r = 0; r < 4; r++) {
      int oc = oc0 + lg * 4 + r;
      if (oc < 32) y_q[(size_t)(b * 32 + oc) * S_TOT + sp] = acc[r];
      else         y_kv[(size_t)(b * 128 + oc - 32) * S_TOT + sp] = acc[r];
    }
  }
}

// ---------------------------------------------------------------------------
// K2a: per-channel (sum, sumsq) reduction straight over y rows (coalesced).
__global__ __launch_bounds__(256) void k_red(
    const float* __restrict__ y_q, const float* __restrict__ y_kv,
    double* __restrict__ SQ) {
  const int pair = blockIdx.x, tid = threadIdx.x;
  const int lane = tid & 63, wid = tid >> 6;
  const int b = pair / 160, c = pair % 160;
  const float* row = (c < 32) ? y_q + ((size_t)(b * 32 + c) << 12)
                              : y_kv + ((size_t)(b * 128 + c - 32) << 12);
  const float4* r4 = (const float4*)row;
  double s = 0, q = 0;
#pragma unroll
  for (int j = 0; j < 4; j++) {
    float4 v = r4[tid * 4 + j];
    s += (double)v.x + (double)v.y + (double)v.z + (double)v.w;
    q += (double)v.x * v.x + (double)v.y * v.y + (double)v.z * v.z + (double)v.w * v.w;
  }
#pragma unroll
  for (int o = 1; o < 64; o <<= 1) { s += __shfl_xor(s, o, 64); q += __shfl_xor(q, o, 64); }
  __shared__ double red[4][2];
  if (lane == 0) { red[wid][0] = s; red[wid][1] = q; }
  __syncthreads();
  if (tid == 0) {
    SQ[pair * 2]     = red[0][0] + red[1][0] + red[2][0] + red[3][0];
    SQ[pair * 2 + 1] = red[0][1] + red[1][1] + red[2][1] + red[3][1];
  }
}

// K2b: compose group-norms into per-channel affine coefs + fill rope trig table.
__global__ __launch_bounds__(512) void k_stats(
    const double* __restrict__ SQ,
    const float* __restrict__ qg, const float* __restrict__ qb,
    const float* __restrict__ kvg, const float* __restrict__ kvb,
    const float* __restrict__ kng, const float* __restrict__ knb,
    float* __restrict__ coef, float2* __restrict__ tab) {
  __shared__ double Sh[2][160], Qh[2][160];
  const int tid = threadIdx.x;
  for (int i = tid; i < 1024; i += 512) {
    int src = i >> 4, j = i & 15;
    float inv = exp2f(-(float)j * L2_10000_D16);
    float ang = (float)src * inv;
    tab[i] = make_float2(sinf(ang), cosf(ang));
  }
  if (tid < 320) {
    int b = tid / 160, c = tid % 160;
    Sh[b][c] = SQ[tid * 2]; Qh[b][c] = SQ[tid * 2 + 1];
  }
  __syncthreads();
  if (tid < 2) {
    int b = tid;
    float* cf = coef + b * 320;
    const double NS = 4096.0;
    double muq = 0, m2q = 0;
    for (int c = 0; c < 32; c++) { muq += Sh[b][c]; m2q += Qh[b][c]; }
    muq /= (32.0 * NS); m2q /= (32.0 * NS);
    double rstdq = 1.0 / sqrt(m2q - muq * muq + 1e-5);
    for (int c = 0; c < 32; c++) {
      double A = rstdq * (double)qg[c];
      cf[c] = (float)A; cf[32 + c] = (float)((double)qb[c] - muq * A);
    }
    double mukv = 0, m2kv = 0;
    for (int c = 0; c < 128; c++) { mukv += Sh[b][32 + c]; m2kv += Qh[b][32 + c]; }
    mukv /= (128.0 * NS); m2kv /= (128.0 * NS);
    double rstdkv = 1.0 / sqrt(m2kv - mukv * mukv + 1e-5);
    for (int c = 0; c < 64; c++) {
      double A = rstdkv * (double)kvg[c];
      cf[64 + c] = (float)A; cf[128 + c] = (float)((double)kvb[c] - mukv * A);
    }
    double mu2 = 0, m22 = 0;
    for (int c2 = 0; c2 < 64; c2++) {
      int c = 64 + c2;
      double a = rstdkv * (double)kvg[c], bb = (double)kvb[c] - mukv * a;
      double Ec = Sh[b][32 + c] / NS, M2c = Qh[b][32 + c] / NS;
      mu2 += a * Ec + bb;
      m22 += a * a * M2c + 2.0 * a * bb * Ec + bb * bb;
    }
    mu2 /= 64.0; m22 /= 64.0;
    double rstd2 = 1.0 / sqrt(m22 - mu2 * mu2 + 1e-5);
    for (int c2 = 0; c2 < 64; c2++) {
      int c = 64 + c2;
      double a = rstdkv * (double)kvg[c], bb = (double)kvb[c] - mukv * a;
      cf[192 + c2] = (float)(a * rstd2 * (double)kng[c2]);
      cf[256 + c2] = (float)((bb - mu2) * rstd2 * (double)kng[c2] + (double)knb[c2]);
    }
  }
}

// ---------------------------------------------------------------------------
// K3: latent build only (Q build is fused into k_attn). grid B*64.
__global__ __launch_bounds__(256) void k_lat(
    const float* __restrict__ y_kv, const float* __restrict__ coef,
    const float2* __restrict__ tab, ushort_t* __restrict__ C, ushort_t* __restrict__ VT) {
  const int blk = blockIdx.x;
  const int b = blk >> 6, st = (blk & 63) * 64;
  const int t = threadIdx.x, si = t & 63, g = t >> 6;
  const float* cf = coef + b * 320;
  const int sp = st + si;
  if (g < 2) {
    const int c0 = g * 32;
    float v[32];
#pragma unroll
    for (int j = 0; j < 32; j++) {
      int c = c0 + j;
      v[j] = y_kv[(size_t)(b * 128 + c) * S_TOT + sp] * cf[64 + c] + cf[128 + c];
    }
    const int hi = sp >> 6, wi = sp & 63;
#pragma unroll
    for (int k = 0; k < 16; k++)
      rope_pair_t(v[2 * k], v[2 * k + 1], (c0 >> 1) + k, hi, wi, 1.0f, tab);
    ushort_t pk[32];
#pragma unroll
    for (int j = 0; j < 32; j++) pk[j] = f2b(v[j]);
    ushort_t* crow = C + (size_t)(b * S_TOT + sp) * 128 + 64 + c0;
#pragma unroll
    for (int j4 = 0; j4 < 4; j4++) *(s16x8*)(crow + j4 * 8) = *(s16x8*)(pk + j4 * 8);
  } else {
    const int c0 = (g - 2) * 32;
    ushort_t pk[32];
#pragma unroll
    for (int j = 0; j < 32; j++) {
      int c2 = c0 + j;
      float v = y_kv[(size_t)(b * 128 + 64 + c2) * S_TOT + sp] * cf[192 + c2] + cf[256 + c2];
      ushort_t u = f2b(v);
      pk[j] = u;
      VT[(size_t)(b * 64 + c2) * S_TOT + sp] = u;
    }
    ushort_t* crow = C + (size_t)(b * S_TOT + sp) * 128 + c0;
#pragma unroll
    for (int j4 = 0; j4 < 4; j4++) *(s16x8*)(crow + j4 * 8) = *(s16x8*)(pk + j4 * 8);
  }
}

// ---------------------------------------------------------------------------
// K5: flash attention with FUSED Q build (prologue computes qf[] from y_q via
// MFMA + rope, assembling fragments with cvt_pk + permlane32_swap — same
// geometry as the validated PV path). Main loop unchanged (round-13 structure).
// grid 512 = 2 half x 8 bh x 32 qblk. LDS 72 KB.
__global__ __launch_bounds__(256, 2) void k_attn(
    const float* __restrict__ y_q, const float* __restrict__ coef,
    const ushort_t* __restrict__ wq2, const float* __restrict__ q2b2,
    const float2* __restrict__ tab,
    const ushort_t* __restrict__ C, const ushort_t* __restrict__ VT,
    ushort_t* __restrict__ Opart, float* __restrict__ lvec) {
  const int bid = blockIdx.x;
  const int bh = bid & 7;                  // XCD swizzle: one bh per XCD
  const int rest = bid >> 3;               // [0,64)
  const int half = rest >> 5, qblk = rest & 31;
  const int kv0 = half * 2048;
  const int tid = threadIdx.x;
  const int wid = tid >> 6, lane = tid & 63;
  const int l31 = lane & 31, hi = lane >> 5;
  const int qbase = qblk * 128 + wid * 32;
  const int b4 = bh >> 2;                  // batch index
  const ushort_t* Kp = C + (size_t)b4 * S_TOT * 128;
  const ushort_t* Vp = VT + (size_t)b4 * 64 * S_TOT;

  __shared__ __align__(16) ushort_t K_lds[3][64][128];  // 48 KB
  __shared__ __align__(16) ushort_t V_lds[3][64][64];   // 24 KB

  s16x8 qf[8];
  // ---- fused Q build prologue ----
  {
    ushort_t* Xq = (ushort_t*)&K_lds[0][0][0];   // [128][64] ushort rows (128B), 16 KB
    const float* cf = coef + b4 * 320;
    {
      const int si = tid & 127, g = tid >> 7;
      ushort_t pk[16];
#pragma unroll
      for (int j = 0; j < 16; j++) {
        int c = g * 16 + j;
        float v = y_q[(size_t)(b4 * 32 + c) * S_TOT + qblk * 128 + si];
        pk[j] = f2b(v * cf[c] + cf[32 + c]);
      }
      *(s16x8*)((char*)(Xq + si * 64) + ((g * 32) ^ ((si & 7) << 4))) = *(s16x8*)pk;
      *(s16x8*)((char*)(Xq + si * 64) + ((g * 32 + 16) ^ ((si & 7) << 4))) = *(s16x8*)(pk + 8);
    }
    __syncthreads();
    const int h = bh & 3;
    const int qrow = wid * 32 + l31;
    const int qsw = (qrow & 7) << 4;
    const int sp = qbase + l31, hip = sp >> 6, wip = sp & 63;
#pragma unroll
    for (int tq = 0; tq < 4; tq++) {
      f32x16 dq;
#pragma unroll
      for (int r = 0; r < 16; r++)
        dq[r] = q2b2[h * 128 + 32 * tq + (r & 3) + 8 * (r >> 2) + 4 * hi];
#pragma unroll
      for (int kk = 0; kk < 2; kk++) {
        s16x8 wf = *(const s16x8*)(wq2 + (size_t)(h * 128 + tq * 32 + l31) * 32 + kk * 16 + hi * 8);
        s16x8 xf = *(const s16x8*)((const char*)(Xq + qrow * 64) + ((kk * 32 + hi * 16) ^ qsw));
        dq = __builtin_amdgcn_mfma_f32_32x32x16_bf16(wf, xf, dq, 0, 0, 0);
      }
#pragma unroll
      for (int m = 0; m < 8; m++) {
        const int r = 2 * m;
        const int dg = 32 * tq + (r & 3) + 8 * (r >> 2) + 4 * hi;
        float v0 = dq[r], v1 = dq[r + 1];
        if (tq >= 2) rope_pair_t(v0, v1, (dg - 64) >> 1, hip, wip, QSL, tab);
        else { v0 *= QSL; v1 *= QSL; }
        dq[r] = v0; dq[r + 1] = v1;
      }
#pragma unroll
      for (int hc = 0; hc < 2; hc++) {
        const int rA = 8 * hc;
        uint_t a0 = cvt_pk_bf16(dq[rA + 0], dq[rA + 1]);
        uint_t a1 = cvt_pk_bf16(dq[rA + 2], dq[rA + 3]);
        uint_t b0 = cvt_pk_bf16(dq[rA + 4], dq[rA + 5]);
        uint_t b1 = cvt_pk_bf16(dq[rA + 6], dq[rA + 7]);
        asm volatile("v_permlane32_swap_b32 %0, %1" : "+v"(a0), "+v"(b0));
        asm volatile("v_permlane32_swap_b32 %0, %1" : "+v"(a1), "+v"(b1));
        union { uint_t u[4]; s16x8 v; } pfq;
        pfq.u[0] = a0; pfq.u[1] = a1; pfq.u[2] = b0; pfq.u[3] = b1;
        qf[2 * tq + hc] = pfq.v;
      }
    }
    __syncthreads();   // all Xq reads done before STAGE overwrites K_lds[0]
  }

  f32x16 o0, o1;
#pragma unroll
  for (int r = 0; r < 16; r++) { o0[r] = 0.f; o1[r] = 0.f; }
  float l_s = 0.f;

  const int krow_l = tid >> 4;   // +i*16
  const int kcolb = (tid & 15) * 16;
  const int vrow_l = tid >> 3;   // +i*32
  const int vcolb = (tid & 7) * 16;

#define STAGE(kvb, bufi)                                                          \
  {                                                                               \
    _Pragma("unroll")                                                             \
    for (int i = 0; i < 4; i++) {                                                 \
      int row = i * 16 + krow_l;                                                  \
      int colb = kcolb ^ ((row & 15) << 4);                                       \
      gload16((const char*)(Kp + (size_t)((kvb) + row) * 128) + colb,             \
              (void*)&K_lds[bufi][i * 16 + wid * 4][0]);                          \
    }                                                                             \
    _Pragma("unroll")                                                             \
    for (int i = 0; i < 2; i++) {                                                 \
      int vd = i * 32 + vrow_l;                                                   \
      int colb = vcolb ^ ((vd & 7) << 4);                                         \
      gload16((const char*)(Vp + (size_t)vd * S_TOT + (kvb)) + colb,              \
              (void*)&V_lds[bufi][i * 32 + wid * 8][0]);                          \
    }                                                                             \
  }

  STAGE(kv0, 0);            // 6 loads
  STAGE(kv0 + 64, 1);       // 12 outstanding

  const int kswz = (l31 & 15) << 4;
  const int vswz = (l31 & 7) << 4;
#pragma unroll 1
  for (int t = 0; t < 32; t++) {
    const int buf = t % 3;
    if (t < 31) {
      asm volatile("s_waitcnt vmcnt(6)" ::: "memory");   // own buf-t loads done
    } else {
      asm volatile("s_waitcnt vmcnt(0)" ::: "memory");
    }
    __builtin_amdgcn_sched_barrier(0);
    __builtin_amdgcn_s_barrier();          // publishes everyone's buf-t loads
    __builtin_amdgcn_sched_barrier(0);
    if (t < 30) STAGE(kv0 + (t + 2) * 64, (t + 2) % 3);  // flies for ~2 iters
    f32x16 sc0, sc1;
#pragma unroll
    for (int r = 0; r < 16; r++) { sc0[r] = 0.f; sc1[r] = 0.f; }
    __builtin_amdgcn_s_setprio(1);
#pragma unroll
    for (int c = 0; c < 8; c++) {
      const int off = (c * 32 + hi * 16) ^ kswz;
      s16x8 k0 = *(const s16x8*)((const char*)&K_lds[buf][l31][0] + off);
      s16x8 k1 = *(const s16x8*)((const char*)&K_lds[buf][32 + l31][0] + off);
      sc0 = __builtin_amdgcn_mfma_f32_32x32x16_bf16(k0, qf[c], sc0, 0, 0, 0);
      sc1 = __builtin_amdgcn_mfma_f32_32x32x16_bf16(k1, qf[c], sc1, 0, 0, 0);
    }
    __builtin_amdgcn_s_setprio(0);
    // fixed-reference softmax numerator: P = exp2(s) directly
    float rs = 0.f;
#pragma unroll
    for (int r = 0; r < 16; r++) {
      float p0 = exp2f(sc0[r]);
      float p1 = exp2f(sc1[r]);
      sc0[r] = p0; sc1[r] = p1;
      rs += p0 + p1;
    }
    l_s += rs;
    __builtin_amdgcn_s_setprio(1);
#pragma unroll
    for (int c = 0; c < 4; c++) {
      const f32x16 P = (c < 2) ? sc0 : sc1;
      const int rA = 8 * (c & 1);
      uint_t a0 = cvt_pk_bf16(P[rA + 0], P[rA + 1]);
      uint_t a1 = cvt_pk_bf16(P[rA + 2], P[rA + 3]);
      uint_t b0 = cvt_pk_bf16(P[rA + 4], P[rA + 5]);
      uint_t b1 = cvt_pk_bf16(P[rA + 6], P[rA + 7]);
      asm volatile("v_permlane32_swap_b32 %0, %1" : "+v"(a0), "+v"(b0));
      asm volatile("v_permlane32_swap_b32 %0, %1" : "+v"(a1), "+v"(b1));
      union { uint_t u[4]; s16x8 v; } pf;
      pf.u[0] = a0; pf.u[1] = a1;
      pf.u[2] = b0; pf.u[3] = b1;
      const int voff = (c * 32 + hi * 16) ^ vswz;
      s16x8 v0 = *(const s16x8*)((const char*)&V_lds[buf][l31][0] + voff);
      s16x8 v1 = *(const s16x8*)((const char*)&V_lds[buf][32 + l31][0] + voff);
      o0 = __builtin_amdgcn_mfma_f32_32x32x16_bf16(v0, pf.v, o0, 0, 0, 0);
      o1 = __builtin_amdgcn_mfma_f32_32x32x16_bf16(v1, pf.v, o1, 0, 0, 0);
    }
    __builtin_amdgcn_s_setprio(0);
  }
#undef STAGE
  l_s += __shfl_xor(l_s, 32, 64);
  if (lane < 32)
    lvec[((size_t)(half * 8 + bh) << 12) + qbase + l31] = l_s;
  // O^T -> O epilogue via LDS bounce (reuse K_lds[0]); UNNORMALIZED output
  char* sO = (char*)&K_lds[0][0][0];
#pragma unroll
  for (int vt = 0; vt < 2; vt++) {
#pragma unroll
    for (int r = 0; r < 16; r += 2) {
      float v0 = (vt ? o1[r] : o0[r]);
      float v1 = (vt ? o1[r + 1] : o0[r + 1]);
      uint_t u = cvt_pk_bf16(v0, v1);
      int vd = vt * 32 + (r & 3) + 8 * (r >> 2) + 4 * hi;
      *(uint_t*)(sO + (wid * 32 + l31) * 128 + ((vd * 2) ^ ((l31 & 7) << 4))) = u;
    }
  }
  __syncthreads();
  {
    const int r = tid >> 1, hf = tid & 1;
    const int w = r >> 5, ql = r & 31;
    ushort_t* orow = Opart + ((size_t)(half * 8 + bh) * S_TOT + qblk * 128 + r) * 64 + hf * 32;
#pragma unroll
    for (int j = 0; j < 4; j++) {
      s16x8 v = *(const s16x8*)(sO + (w * 32 + ql) * 128 + ((hf * 64 + j * 16) ^ ((ql & 7) << 4)));
      *(s16x8*)(orow + j * 8) = v;
    }
  }
}

// ---------------------------------------------------------------------------
// K6: out conv (absorbed W_v) + fused combine: X = (O0_raw + O1_raw)/(l0+l1).
__global__ __launch_bounds__(256) void k_oc(
    const ushort_t* __restrict__ Opart, const float* __restrict__ lvec,
    const ushort_t* __restrict__ wout, const float* __restrict__ outb2,
    const float* __restrict__ x, float* __restrict__ out) {
  const int id = blockIdx.x;
  const int cch = id & 1, st32 = (id >> 1) & 127, b = id >> 8;
  const int t = threadIdx.x, wid = t >> 6;
  const int l15 = t & 15, lg = (t >> 4) & 3;
  __shared__ __align__(16) ushort_t Xt[32][256];
  {
    const int s = t & 31, grp = t >> 5;
    const int h = grp >> 1, vd0 = (grp & 1) * 32;
    const int sp = st32 * 32 + s;
    const float l0 = lvec[((size_t)(b * 4 + h) << 12) + sp];
    const float l1 = lvec[((size_t)(8 + b * 4 + h) << 12) + sp];
    const float w = 1.f / (l0 + l1);
    const ushort_t* oa = Opart + ((size_t)(b * 4 + h) * S_TOT + sp) * 64 + vd0;
    const ushort_t* obp = oa + (size_t)8 * S_TOT * 64;
#pragma unroll
    for (int j4 = 0; j4 < 4; j4++) {
      union { s16x8 v; ushort_t u[8]; } av, bv2;
      av.v = *(const s16x8*)(oa + j4 * 8);
      bv2.v = *(const s16x8*)(obp + j4 * 8);
      ushort_t pk[8];
#pragma unroll
      for (int j = 0; j < 8; j++) pk[j] = f2b(w * (b2f(av.u[j]) + b2f(bv2.u[j])));
      *(s16x8*)((char*)&Xt[s][0] + ((grp * 64 + j4 * 16) ^ ((s & 7) << 4))) = *(s16x8*)pk;
    }
  }
  __syncthreads();
  const int c0w = cch * 64 + wid * 16;
  f32x4 acc[2];
  {
    f32x4 bv;
#pragma unroll
    for (int r = 0; r < 4; r++) bv[r] = outb2[c0w + lg * 4 + r];
    acc[0] = bv; acc[1] = bv;
  }
#pragma unroll
  for (int kk = 0; kk < 8; kk++) {
    s16x8 wf = *(const s16x8*)(wout + (size_t)(c0w + l15) * 256 + kk * 32 + lg * 8);
#pragma unroll
    for (int sb = 0; sb < 2; sb++) {
      s16x8 xf = *(const s16x8*)((const char*)&Xt[sb * 16 + l15][0] +
                                 ((kk * 64 + lg * 16) ^ ((l15 & 7) << 4)));
      acc[sb] = __builtin_amdgcn_mfma_f32_16x16x32_bf16(wf, xf, acc[sb], 0, 0, 0);
    }
  }
#pragma unroll
  for (int sb = 0; sb < 2; sb++) {
#pragma unroll
    for (int r = 0; r < 4; r++) {
      int c = c0w + lg * 4 + r;
      int sp = st32 * 32 + sb * 16 + l15;
      size_t idx = (size_t)(b * 128 + c) * S_TOT + sp;
      out[idx] = acc[sb][r] + x[idx];
    }
  }
}

// ---------------------------------------------------------------------------
extern "C" void kernel_launch(void* const* d_in, const int* in_sizes, int n_in,
                              void* d_out, int out_size, void* d_ws, size_t ws_size,
                              hipStream_t stream) {
  const float* x      = (const float*)d_in[0];
  const float* q1_w   = (const float*)d_in[1];
  const float* q1_b   = (const float*)d_in[2];
  const float* q_gn_g = (const float*)d_in[3];
  const float* q_gn_b = (const float*)d_in[4];
  const float* q2_w   = (const float*)d_in[5];
  const float* q2_b   = (const float*)d_in[6];
  const float* kv1_w  = (const float*)d_in[7];
  const float* kv1_b  = (const float*)d_in[8];
  const float* kv_gn_g= (const float*)d_in[9];
  const float* kv_gn_b= (const float*)d_in[10];
  const float* kvn_g  = (const float*)d_in[11];
  const float* kvn_b  = (const float*)d_in[12];
  const float* kvup_w = (const float*)d_in[13];
  const float* kvup_b = (const float*)d_in[14];
  const float* out_w  = (const float*)d_in[15];
  const float* out_b  = (const float*)d_in[16];

  const size_t MB = 1u << 20;
  char* ws = (char*)d_ws;
  float*    y_q   = (float*)(ws);                           // 0..1 MB
  float*    y_kv  = (float*)(ws + 1 * MB);                  // 1..5 MB
  ushort_t* C     = (ushort_t*)(ws + 13 * MB);              // 13..15 MB (latent+rope)
  ushort_t* VT    = (ushort_t*)(ws + 15 * MB);              // 15..16 MB (latent^T)
  double*   SQ    = (double*)(ws + 19 * MB);                // 5 KB
  float*    coef  = (float*)(ws + 19 * MB + 8192);          // 2.5 KB
  ushort_t* wq2   = (ushort_t*)(ws + 19 * MB + 16384);      // 32 KB
  ushort_t* wout  = (ushort_t*)(ws + 19 * MB + 65536);      // 64 KB
  float*    q2b2  = (float*)(ws + 19 * MB + 131072);        // 2 KB
  float*    outb2 = (float*)(ws + 19 * MB + 139264);        // 512 B
  float2*   tab   = (float2*)(ws + 19 * MB + 143360);       // 8 KB rope trig table
  ushort_t* Opart = (ushort_t*)(ws + 20 * MB);              // 20..28 MB
  float*    lvec  = (float*)(ws + 28 * MB);                 // 256 KB
  float*    out   = (float*)d_out;

  k_conv1<<<451, 256, 0, stream>>>(x, q1_w, q1_b, kv1_w, kv1_b, y_q, y_kv,
                                   q2_w, q2_b, kvup_w, kvup_b, out_w, out_b,
                                   wq2, wout, q2b2, outb2);
  k_red  <<<320, 256, 0, stream>>>(y_q, y_kv, SQ);
  k_stats<<<1,   512, 0, stream>>>(SQ, q_gn_g, q_gn_b, kv_gn_g, kv_gn_b, kvn_g, kvn_b,
                                   coef, tab);
  k_lat  <<<128, 256, 0, stream>>>(y_kv, coef, tab, C, VT);
  k_attn <<<512, 256, 0, stream>>>(y_q, coef, wq2, q2b2, tab, C, VT, Opart, lvec);
  k_oc   <<<512, 256, 0, stream>>>(Opart, lvec, wout, outb2, x, out);
}